// Round 12
// baseline (117.873 us; speedup 1.0000x reference)
//
#include <hip/hip_runtime.h>
#include <hip/hip_bf16.h>

#define BB 8
#define NN 2048
#define CC 320
#define CQ 64
#define LOG2E 1.4426950408889634f

typedef __attribute__((ext_vector_type(8)))  short bf16x8;
typedef __attribute__((ext_vector_type(4)))  float f32x4;
typedef __attribute__((ext_vector_type(16))) float f32x16;
typedef __attribute__((ext_vector_type(4)))  unsigned short us4;
typedef __attribute__((ext_vector_type(8)))  unsigned short us8;
typedef __attribute__((ext_vector_type(4)))  unsigned int u32x4;
typedef unsigned short u16;

// Layouts:
//  Q3[b][kt=k/32][cq8=cq/8][kl=k%32][8]  (bf16, pre-scaled by log2e)
//  Kb[b*N+n][cq]                          (row-major)
//  V3[b][kt8=k/8][c][8]                   (bf16, scaled by 1/S[k] in K3)

static __device__ __forceinline__ u16 f2b(float f) {
  unsigned u = __builtin_bit_cast(unsigned, f);
  unsigned r = (u + 0x7FFFu + ((u >> 16) & 1u)) >> 16;
  return (u16)r;
}
static __device__ __forceinline__ float b2f(u16 s) {
  unsigned u = ((unsigned)s) << 16;
  return __builtin_bit_cast(float, u);
}

static __device__ __forceinline__ f32x16 zero16() {
  f32x16 v = {0,0,0,0, 0,0,0,0, 0,0,0,0, 0,0,0,0};
  return v;
}
static __device__ __forceinline__ f32x4 zero4() {
  f32x4 v = {0,0,0,0};
  return v;
}

static __device__ __forceinline__ void gll16(const void* g, void* l) {
  __builtin_amdgcn_global_load_lds(
      (const __attribute__((address_space(1))) unsigned int*)g,
      (__attribute__((address_space(3))) unsigned int*)l, 16, 0, 0);
}

// 8 fp32 -> bf16x8 via hardware packed converts (RNE, same as f2b)
static __device__ __forceinline__ bf16x8 cvt8(float4 a, float4 b) {
  unsigned p0, p1, p2, p3;
  asm("v_cvt_pk_bf16_f32 %0, %1, %2" : "=v"(p0) : "v"(a.x), "v"(a.y));
  asm("v_cvt_pk_bf16_f32 %0, %1, %2" : "=v"(p1) : "v"(a.z), "v"(a.w));
  asm("v_cvt_pk_bf16_f32 %0, %1, %2" : "=v"(p2) : "v"(b.x), "v"(b.y));
  asm("v_cvt_pk_bf16_f32 %0, %1, %2" : "=v"(p3) : "v"(b.z), "v"(b.w));
  u32x4 w = {p0, p1, p2, p3};
  return __builtin_bit_cast(bf16x8, w);
}

// ---------------------------------------------------------------------------
// K1: QKV GEMM, fp32 inputs converted in-register (no cvt pre-pass).
// grid (7, 128). x=0: Q -> Q3 blocked (scaled by log2e), x=1: K -> Kb
// row-major, x>=2: V -> V3 blocked.
// ---------------------------------------------------------------------------
__global__ __launch_bounds__(256) void gemm_qkv(
    const float* __restrict__ x,
    const float* __restrict__ Wq, const float* __restrict__ Wk,
    const float* __restrict__ Wv,
    const float* __restrict__ bq, const float* __restrict__ bk,
    const float* __restrict__ bv,
    u16* __restrict__ Qb, u16* __restrict__ Kb, u16* __restrict__ Vt) {
  const int tid = threadIdx.x;
  const int lane = tid & 63, wid = tid >> 6;
  const int r = lane & 31, h = lane >> 5;
  const int m0 = blockIdx.y * 128 + wid * 32;
  const int col0 = blockIdx.x * 64;

  const float* Wsel; int wrow0;
  if (col0 < 64)       { Wsel = Wq; wrow0 = col0; }
  else if (col0 < 128) { Wsel = Wk; wrow0 = col0 - 64; }
  else                 { Wsel = Wv; wrow0 = col0 - 128; }

  f32x16 acc0 = zero16(), acc1 = zero16();
  const float* xrow = x + (size_t)(m0 + r) * CC + h * 8;
  const float* w0p = Wsel + (size_t)(wrow0 + r) * CC + h * 8;
  const float* w1p = w0p + 32 * CC;

  float4 xa  = *(const float4*)(xrow),     xb4 = *(const float4*)(xrow + 4);
  float4 wa0 = *(const float4*)(w0p),      wb0 = *(const float4*)(w0p + 4);
  float4 wa1 = *(const float4*)(w1p),      wb1 = *(const float4*)(w1p + 4);
#pragma unroll 1
  for (int ks = 0; ks < 20; ++ks) {
    float4 nxa, nxb, nwa0, nwb0, nwa1, nwb1;
    if (ks < 19) {
      nxa  = *(const float4*)(xrow + (ks + 1) * 16);
      nxb  = *(const float4*)(xrow + (ks + 1) * 16 + 4);
      nwa0 = *(const float4*)(w0p + (ks + 1) * 16);
      nwb0 = *(const float4*)(w0p + (ks + 1) * 16 + 4);
      nwa1 = *(const float4*)(w1p + (ks + 1) * 16);
      nwb1 = *(const float4*)(w1p + (ks + 1) * 16 + 4);
    }
    bf16x8 a  = cvt8(xa, xb4);
    bf16x8 b0 = cvt8(wa0, wb0);
    bf16x8 b1 = cvt8(wa1, wb1);
    acc0 = __builtin_amdgcn_mfma_f32_32x32x16_bf16(a, b0, acc0, 0, 0, 0);
    acc1 = __builtin_amdgcn_mfma_f32_32x32x16_bf16(a, b1, acc1, 0, 0, 0);
    xa = nxa; xb4 = nxb; wa0 = nwa0; wb0 = nwb0; wa1 = nwa1; wb1 = nwb1;
  }

  const int bb = m0 >> 11;        // batch
  const int mloc = m0 & 2047;     // n (or k) within batch

#pragma unroll
  for (int nt = 0; nt < 2; ++nt) {
    const int col = col0 + nt * 32 + r;
    const f32x16 A = nt ? acc1 : acc0;
    if (col0 >= 128) {
      // V3[b][kt8][c][8]: group g holds rows mloc + g*8 + 4h + {0..3}
      const int c = col - 128;
      const float bias = bv[c];
      u16* vdst = Vt + (((size_t)(bb * 256 + (mloc >> 3)) * 320 + c) * 8) + 4 * h;
#pragma unroll
      for (int g = 0; g < 4; ++g) {
        us4 o;
#pragma unroll
        for (int e = 0; e < 4; ++e) o[e] = f2b(A[g * 4 + e] + bias);
        *(us4*)(vdst + (size_t)g * 2560) = o;   // next kt8: +320*8
      }
    } else if (col0 >= 64) {
      const float bias = bk[col - 64];
#pragma unroll
      for (int reg = 0; reg < 16; ++reg) {
        const int row = m0 + (reg & 3) + 8 * (reg >> 2) + 4 * h;
        Kb[(size_t)row * CQ + (col - 64)] = f2b(A[reg] + bias);
      }
    } else {
      // Q3[b][kt][cq8][kl][8], pre-scaled by log2(e)
      const float bias = bq[col];
      const int kt = mloc >> 5;
      u16* qdst = Qb + (((size_t)(bb * 64 + kt) * 8 + (col >> 3)) * 32) * 8 + (col & 7);
#pragma unroll
      for (int reg = 0; reg < 16; ++reg) {
        const int kl = (reg & 3) + 8 * (reg >> 2) + 4 * h;
        qdst[kl * 8] = f2b((A[reg] + bias) * LOG2E);
      }
    }
  }
}

// ---------------------------------------------------------------------------
// K3: row sums + fold 1/S into V3. 8 waves (512 thr), grid 256 (8b x 32 kblk).
// S[k] = sum_m 2^(Q'[k]·K[m]); then V3[b][k][c] *= 1/S[k] for all c.
// ---------------------------------------------------------------------------
__global__ __launch_bounds__(512) void row_stats(
    const u16* __restrict__ Qb, const u16* __restrict__ Kb,
    u16* __restrict__ Vt) {
  __shared__ float Sp[8][64];
  __shared__ float sInv[64];
  const int tid = threadIdx.x;
  const int lane = tid & 63, wid = tid >> 6;   // 0..7
  const int rl = lane & 15, hq = lane >> 4;
  const int bid = blockIdx.x;
  const int batch = bid & 7;
  const int kloc64 = (bid >> 3) * 64;          // bid>>3 in [0,32)

  // A-frags from Q3: rows kloc64 + mt*16 + rl, cq = qs*32 + hq*8
  bf16x8 af[4][2];
#pragma unroll
  for (int mt = 0; mt < 4; ++mt) {
    const int k_loc = kloc64 + mt * 16 + rl;
    const int kt = k_loc >> 5, kl = k_loc & 31;
#pragma unroll
    for (int qs = 0; qs < 2; ++qs)
      af[mt][qs] = *(const bf16x8*)(Qb +
          (((size_t)(batch * 64 + kt) * 8 + qs * 4 + hq) * 32 + kl) * 8);
  }

  float S[4][4];
#pragma unroll
  for (int mt = 0; mt < 4; ++mt)
#pragma unroll
    for (int rr = 0; rr < 4; ++rr) S[mt][rr] = 0.f;

  const int mstart = batch * NN + wid * 256;
  const u16* kr = Kb + (size_t)(mstart + rl) * CQ + hq * 8;
  bf16x8 c0 = *(const bf16x8*)(kr);
  bf16x8 c1 = *(const bf16x8*)(kr + 32);
#pragma unroll 1
  for (int ms = 0; ms < 16; ++ms) {
    bf16x8 n0, n1;
    if (ms < 15) {
      n0 = *(const bf16x8*)(kr + 16 * CQ);
      n1 = *(const bf16x8*)(kr + 16 * CQ + 32);
    }
#pragma unroll
    for (int mt = 0; mt < 4; ++mt) {
      f32x4 e = zero4();
      e = __builtin_amdgcn_mfma_f32_16x16x32_bf16(af[mt][0], c0, e, 0, 0, 0);
      e = __builtin_amdgcn_mfma_f32_16x16x32_bf16(af[mt][1], c1, e, 0, 0, 0);
#pragma unroll
      for (int rr = 0; rr < 4; ++rr) S[mt][rr] += __builtin_amdgcn_exp2f(e[rr]);
    }
    c0 = n0; c1 = n1; kr += 16 * CQ;
  }

#pragma unroll
  for (int d = 1; d < 16; d <<= 1)
#pragma unroll
    for (int mt = 0; mt < 4; ++mt)
#pragma unroll
      for (int rr = 0; rr < 4; ++rr) S[mt][rr] += __shfl_xor(S[mt][rr], d, 64);

  if (rl == 0) {
#pragma unroll
    for (int mt = 0; mt < 4; ++mt)
#pragma unroll
      for (int rr = 0; rr < 4; ++rr) Sp[wid][mt * 16 + hq * 4 + rr] = S[mt][rr];
  }
  __syncthreads();
  if (tid < 64) {
    float s = 0.f;
#pragma unroll
    for (int p = 0; p < 8; ++p) s += Sp[p][tid];
    sInv[tid] = 1.0f / s;
  }
  __syncthreads();

  // scale V3[b][kt8b..kt8b+8)[c][8] by sInv — fully coalesced us4 stream
  const int kt8b = kloc64 >> 3;
#pragma unroll 1
  for (int i = 0; i < 10; ++i) {
    const int chunk = i * 512 + tid;     // 0..5119
    const int kt8l = chunk / 640;        // 0..7
    const int rem = chunk - kt8l * 640;  // 0..639
    const int c = rem >> 1;
    const int h2 = rem & 1;
    u16* p = Vt + (((size_t)(batch * 256 + kt8b + kt8l) * 320 + c) * 8) + h2 * 4;
    us4 v = *(const us4*)p;
    us4 o;
#pragma unroll
    for (int e2 = 0; e2 < 4; ++e2) o[e2] = f2b(b2f(v[e2]) * sInv[kt8l * 8 + h2 * 4 + e2]);
    *(us4*)p = o;
  }
}

// ---------------------------------------------------------------------------
// K4: attention v7 (round-10 passing version) — LDS-staged, paired waves.
// Block = 256 thr = 4 waves: (wn = n-tile 0/1) x (kh = k-half 0/1).
// Grid 512 = 8b x 2ch x 32 n-pairs. Per k-tile (32k) the block stages ONCE
// via global_load_lds: Q(4KB) + V(10KB) per kh = 28KB, double-buffered.
// Residual reads x (fp32) directly. batch = bid&7 (XCD-pinned).
// ---------------------------------------------------------------------------
__global__ __launch_bounds__(256, 2) void attn(
    const u16* __restrict__ Qb, const u16* __restrict__ Kb,
    const u16* __restrict__ Vt, const float* __restrict__ x,
    const float* __restrict__ gamma, float* __restrict__ out) {
  __shared__ __align__(16) char LDSRAW[57344];   // 2 bufs x 2 kh x 14336
  const int tid = threadIdx.x;
  const int lane = tid & 63, wid = tid >> 6;
  const int wn = wid >> 1;       // n-tile within pair
  const int kh = wid & 1;        // k-half
  const int r = lane & 31, h = lane >> 5;
  const int bid = blockIdx.x;
  const int b = bid & 7;
  const int rest = bid >> 3;
  const int ch = rest & 1;
  const int n0 = (rest >> 1) * 64;

  // K fragments for n-tile n0 + wn*32 (held all k)
  bf16x8 kf[4];
  {
    const u16* krow = Kb + (size_t)(b * NN + n0 + wn * 32 + r) * CQ + h * 8;
#pragma unroll
    for (int qs = 0; qs < 4; ++qs) kf[qs] = *(const bf16x8*)(krow + qs * 16);
  }

  f32x16 acc[5];
#pragma unroll
  for (int j = 0; j < 5; ++j) acc[j] = zero16();

  // stage: 28 chunks of 1KB (4 Q + 10 V per kh), wave w takes [w*7, w*7+7)
#define STAGE(TN, BUF) {                                                       \
    _Pragma("unroll")                                                          \
    for (int i_ = 0; i_ < 7; ++i_) {                                           \
      const int c_ = wid * 7 + i_;                                             \
      const int khc_ = c_ / 14;                                                \
      const int rem_ = c_ % 14;                                                \
      char* dst_ = LDSRAW + (BUF) * 28672 + khc_ * 14336 + rem_ * 1024;        \
      if (rem_ < 4) {                                                          \
        const u16* src_ = Qb + ((size_t)(b * 64 + khc_ * 32 + (TN)) * 2048)    \
                             + rem_ * 512 + lane * 8;                          \
        gll16(src_, dst_);                                                     \
      } else {                                                                 \
        const int v_ = rem_ - 4;                                               \
        const int off_ = v_ * 512 + lane * 8;                                  \
        const int row_ = off_ / 1280;                                          \
        const int win_ = off_ - row_ * 1280;                                   \
        const u16* src_ = Vt +                                                 \
            ((size_t)(b * 256 + khc_ * 128 + (TN) * 4 + row_) * 320            \
             + ch * 160) * 8 + win_;                                           \
        gll16(src_, dst_);                                                     \
      }                                                                        \
    }                                                                          \
  }

#define COMPUTE(T) {                                                           \
    const char* base_ = LDSRAW + ((T) & 1) * 28672 + kh * 14336;               \
    bf16x8 qf[4];                                                              \
    _Pragma("unroll")                                                          \
    for (int qs = 0; qs < 4; ++qs)                                             \
      qf[qs] = *(const bf16x8*)(base_ + (qs * 2 + h) * 512 + r * 16);          \
    f32x16 e = zero16();                                                       \
    _Pragma("unroll")                                                          \
    for (int qs = 0; qs < 4; ++qs)                                             \
      e = __builtin_amdgcn_mfma_f32_32x32x16_bf16(qf[qs], kf[qs], e, 0, 0, 0); \
    bf16x8 vf[5][2];                                                           \
    _Pragma("unroll")                                                          \
    for (int j = 0; j < 5; ++j)                                                \
      _Pragma("unroll")                                                        \
      for (int ks = 0; ks < 2; ++ks)                                           \
        vf[j][ks] = *(const bf16x8*)(base_ + 4096 + (ks * 2 + h) * 2560        \
                                     + (j * 32 + r) * 16);                     \
    unsigned pk0, pk1, pk2, pk3, pk4, pk5, pk6, pk7;                           \
    { float l0 = __builtin_amdgcn_exp2f(e[0]),  h0 = __builtin_amdgcn_exp2f(e[1]);  \
      float l1 = __builtin_amdgcn_exp2f(e[2]),  h1 = __builtin_amdgcn_exp2f(e[3]);  \
      float l2 = __builtin_amdgcn_exp2f(e[4]),  h2 = __builtin_amdgcn_exp2f(e[5]);  \
      float l3 = __builtin_amdgcn_exp2f(e[6]),  h3 = __builtin_amdgcn_exp2f(e[7]);  \
      float l4 = __builtin_amdgcn_exp2f(e[8]),  h4 = __builtin_amdgcn_exp2f(e[9]);  \
      float l5 = __builtin_amdgcn_exp2f(e[10]), h5 = __builtin_amdgcn_exp2f(e[11]); \
      float l6 = __builtin_amdgcn_exp2f(e[12]), h6 = __builtin_amdgcn_exp2f(e[13]); \
      float l7 = __builtin_amdgcn_exp2f(e[14]), h7 = __builtin_amdgcn_exp2f(e[15]); \
      asm("v_cvt_pk_bf16_f32 %0, %1, %2" : "=v"(pk0) : "v"(l0), "v"(h0));      \
      asm("v_cvt_pk_bf16_f32 %0, %1, %2" : "=v"(pk1) : "v"(l1), "v"(h1));      \
      asm("v_cvt_pk_bf16_f32 %0, %1, %2" : "=v"(pk2) : "v"(l2), "v"(h2));      \
      asm("v_cvt_pk_bf16_f32 %0, %1, %2" : "=v"(pk3) : "v"(l3), "v"(h3));      \
      asm("v_cvt_pk_bf16_f32 %0, %1, %2" : "=v"(pk4) : "v"(l4), "v"(h4));      \
      asm("v_cvt_pk_bf16_f32 %0, %1, %2" : "=v"(pk5) : "v"(l5), "v"(h5));      \
      asm("v_cvt_pk_bf16_f32 %0, %1, %2" : "=v"(pk6) : "v"(l6), "v"(h6));      \
      asm("v_cvt_pk_bf16_f32 %0, %1, %2" : "=v"(pk7) : "v"(l7), "v"(h7)); }    \
    asm("v_permlane32_swap_b32 %0, %1" : "+v"(pk0), "+v"(pk2));                \
    asm("v_permlane32_swap_b32 %0, %1" : "+v"(pk1), "+v"(pk3));                \
    asm("v_permlane32_swap_b32 %0, %1" : "+v"(pk4), "+v"(pk6));                \
    asm("v_permlane32_swap_b32 %0, %1" : "+v"(pk5), "+v"(pk7));                \
    u32x4 w0_ = {pk0, pk1, pk2, pk3};                                          \
    u32x4 w1_ = {pk4, pk5, pk6, pk7};                                          \
    bf16x8 pa0 = __builtin_bit_cast(bf16x8, w0_);                              \
    bf16x8 pa1 = __builtin_bit_cast(bf16x8, w1_);                              \
    _Pragma("unroll")                                                          \
    for (int j = 0; j < 5; ++j) {                                              \
      acc[j] = __builtin_amdgcn_mfma_f32_32x32x16_bf16(pa0, vf[j][0], acc[j], 0, 0, 0); \
      acc[j] = __builtin_amdgcn_mfma_f32_32x32x16_bf16(pa1, vf[j][1], acc[j], 0, 0, 0); \
    }                                                                          \
  }

  STAGE(0, 0);
  __syncthreads();
#pragma unroll 1
  for (int t = 0; t < 32; ++t) {
    if (t < 31) STAGE(t + 1, (t + 1) & 1);
    COMPUTE(t);
    __syncthreads();
  }
#undef STAGE
#undef COMPUTE

  // kh=1 waves dump partial sums; kh=0 waves combine and write out
  float* red = (float*)LDSRAW;   // 2 regions x 5120 f32 = 40 KB
  if (kh == 1) {
#pragma unroll
    for (int reg = 0; reg < 16; ++reg) {
      const int nl = (reg & 3) + 8 * (reg >> 2) + 4 * h;
#pragma unroll
      for (int j = 0; j < 5; ++j)
        red[wn * 5120 + nl * 160 + j * 32 + r] = acc[j][reg];
    }
  }
  __syncthreads();
  if (kh == 0) {
    const float g = gamma[0];
#pragma unroll
    for (int reg = 0; reg < 16; ++reg) {
      const int nl = (reg & 3) + 8 * (reg >> 2) + 4 * h;
      const size_t rowb = ((size_t)(b * NN) + n0 + wn * 32 + nl) * CC + ch * 160 + r;
#pragma unroll
      for (int j = 0; j < 5; ++j) {
        const size_t idx = rowb + (size_t)(j * 32);
        const float s = acc[j][reg] + red[wn * 5120 + nl * 160 + j * 32 + r];
        out[idx] = g * s + x[idx];
      }
    }
  }
}

extern "C" void kernel_launch(void* const* d_in, const int* in_sizes, int n_in,
                              void* d_out, int out_size, void* d_ws, size_t ws_size,
                              hipStream_t stream) {
  const float* x     = (const float*)d_in[0];
  const float* Wq    = (const float*)d_in[1];
  const float* bq    = (const float*)d_in[2];
  const float* Wk    = (const float*)d_in[3];
  const float* bk    = (const float*)d_in[4];
  const float* Wv    = (const float*)d_in[5];
  const float* bv    = (const float*)d_in[6];
  const float* gamma = (const float*)d_in[7];
  float* out = (float*)d_out;

  char* w = (char*)d_ws;
  u16* Qb = (u16*)(w);                         // Q3: 8*64*8*32*8 (2097152 B)
  u16* Kb = (u16*)(w + 2097152);               // 16384*64   (2097152 B)
  u16* Vt = (u16*)(w + 4194304);               // V3: 8*256*320*8 (10485760 B)

  gemm_qkv<<<dim3(7, 128), 256, 0, stream>>>(x, Wq, Wk, Wv, bq, bk, bv, Qb, Kb, Vt);
  row_stats<<<256, 512, 0, stream>>>(Qb, Kb, Vt);
  attn<<<512, 256, 0, stream>>>(Qb, Kb, Vt, x, gamma, out);
}

// Round 13
// 90.667 us; speedup vs baseline: 1.3001x; 1.3001x over previous
//
#include <hip/hip_runtime.h>
#include <hip/hip_bf16.h>

#define BB 8
#define NN 2048
#define CC 320
#define CQ 64
#define LOG2E 1.4426950408889634f

typedef __attribute__((ext_vector_type(8)))  short bf16x8;
typedef __attribute__((ext_vector_type(4)))  float f32x4;
typedef __attribute__((ext_vector_type(16))) float f32x16;
typedef __attribute__((ext_vector_type(4)))  unsigned short us4;
typedef __attribute__((ext_vector_type(8)))  unsigned short us8;
typedef __attribute__((ext_vector_type(4)))  unsigned int u32x4;
typedef unsigned short u16;

// Layouts:
//  X3[mt=m/32][kk8=k/8][ml=m%32][8]       (bf16; lane-contiguous A-frags)
//  W3[ct=c/32][kk8=k/8][cl=c%32][8]       (bf16; lane-contiguous B-frags)
//  Q3[b][kt=k/32][cq8=cq/8][kl=k%32][8]   (bf16, pre-scaled by log2e)
//  Kb[b*N+n][cq]                          (row-major)
//  V3[b][kt8=k/8][c][8]                   (bf16, scaled by 1/S[k] in K3)

static __device__ __forceinline__ u16 f2b(float f) {
  unsigned u = __builtin_bit_cast(unsigned, f);
  unsigned r = (u + 0x7FFFu + ((u >> 16) & 1u)) >> 16;
  return (u16)r;
}
static __device__ __forceinline__ float b2f(u16 s) {
  unsigned u = ((unsigned)s) << 16;
  return __builtin_bit_cast(float, u);
}

static __device__ __forceinline__ f32x16 zero16() {
  f32x16 v = {0,0,0,0, 0,0,0,0, 0,0,0,0, 0,0,0,0};
  return v;
}
static __device__ __forceinline__ f32x4 zero4() {
  f32x4 v = {0,0,0,0};
  return v;
}

static __device__ __forceinline__ void gll16(const void* g, void* l) {
  __builtin_amdgcn_global_load_lds(
      (const __attribute__((address_space(1))) unsigned int*)g,
      (__attribute__((address_space(3))) unsigned int*)l, 16, 0, 0);
}

// 8 fp32 -> bf16x8 via hardware packed converts (RNE, same as f2b)
static __device__ __forceinline__ bf16x8 cvt8(float4 a, float4 b) {
  unsigned p0, p1, p2, p3;
  asm("v_cvt_pk_bf16_f32 %0, %1, %2" : "=v"(p0) : "v"(a.x), "v"(a.y));
  asm("v_cvt_pk_bf16_f32 %0, %1, %2" : "=v"(p1) : "v"(a.z), "v"(a.w));
  asm("v_cvt_pk_bf16_f32 %0, %1, %2" : "=v"(p2) : "v"(b.x), "v"(b.y));
  asm("v_cvt_pk_bf16_f32 %0, %1, %2" : "=v"(p3) : "v"(b.z), "v"(b.w));
  u32x4 w = {p0, p1, p2, p3};
  return __builtin_bit_cast(bf16x8, w);
}

// ---------------------------------------------------------------------------
// K0a: x fp32 -> X3 blocked bf16 via LDS transpose. grid 512 x 256.
// Block b: rows m0=b*32 .. +32, all 320 k.
// ---------------------------------------------------------------------------
__global__ __launch_bounds__(256) void cvt_x_blk(const float* __restrict__ x,
                                                 u16* __restrict__ X3) {
  __shared__ float xs[32][324];   // +4 pad: conflict-free transpose reads
  const int t = threadIdx.x;
  const int b = blockIdx.x;
  const size_t srcb = (size_t)b * 32 * CC;
#pragma unroll
  for (int i = 0; i < 10; ++i) {
    const int lidx = i * 256 + t;        // 0..2559 float4 units
    const int m = lidx / 80;             // 80 float4 per row
    const int kq = lidx - m * 80;
    float4 v = *(const float4*)(x + srcb + (size_t)m * CC + kq * 4);
    *(float4*)&xs[m][kq * 4] = v;
  }
  __syncthreads();
  u16* dst0 = X3 + (size_t)b * 10240;    // 40*256
#pragma unroll
  for (int i = 0; i < 5; ++i) {
    const int u = i * 256 + t;           // 0..1279: kk8*32 + ml
    const int kk8 = u >> 5, ml = u & 31;
    float4 a = *(const float4*)&xs[ml][kk8 * 8];
    float4 c = *(const float4*)&xs[ml][kk8 * 8 + 4];
    bf16x8 o = cvt8(a, c);
    *(bf16x8*)(dst0 + (size_t)u * 8) = o;
  }
}

// ---------------------------------------------------------------------------
// K0b: Wq/Wk/Wv fp32 -> W3 blocked bf16. grid 14 x 256.
// ---------------------------------------------------------------------------
__global__ __launch_bounds__(256) void cvt_w_blk(const float* __restrict__ Wq,
                                                 const float* __restrict__ Wk,
                                                 const float* __restrict__ Wv,
                                                 u16* __restrict__ W3) {
  __shared__ float xs[32][324];
  const int t = threadIdx.x;
  const int b = blockIdx.x;
#pragma unroll
  for (int i = 0; i < 10; ++i) {
    const int lidx = i * 256 + t;
    const int m = lidx / 80;
    const int kq = lidx - m * 80;
    const int row = b * 32 + m;
    const float* src = (row < 64) ? (Wq + (size_t)row * CC)
                     : (row < 128) ? (Wk + (size_t)(row - 64) * CC)
                                   : (Wv + (size_t)(row - 128) * CC);
    float4 v = *(const float4*)(src + kq * 4);
    *(float4*)&xs[m][kq * 4] = v;
  }
  __syncthreads();
  u16* dst0 = W3 + (size_t)b * 10240;
#pragma unroll
  for (int i = 0; i < 5; ++i) {
    const int u = i * 256 + t;
    const int kk8 = u >> 5, ml = u & 31;
    float4 a = *(const float4*)&xs[ml][kk8 * 8];
    float4 c = *(const float4*)&xs[ml][kk8 * 8 + 4];
    bf16x8 o = cvt8(a, c);
    *(bf16x8*)(dst0 + (size_t)u * 8) = o;
  }
}

// ---------------------------------------------------------------------------
// K1: QKV GEMM from blocked X3/W3 (8-line requests) with XCD-aware block
// remap: all 7 col-blocks of one m-tile land on the same XCD -> x slice is
// fetched once and stays L2-resident. grid 896 x 256 (1D).
// ---------------------------------------------------------------------------
__global__ __launch_bounds__(256) void gemm_qkv(
    const u16* __restrict__ X3, const u16* __restrict__ W3,
    const float* __restrict__ bq, const float* __restrict__ bk,
    const float* __restrict__ bv,
    u16* __restrict__ Qb, u16* __restrict__ Kb, u16* __restrict__ Vt) {
  const int tid = threadIdx.x;
  const int lane = tid & 63, wid = tid >> 6;
  const int r = lane & 31, h = lane >> 5;
  const int bid = blockIdx.x;
  const int xcd = bid & 7;
  const int slot = bid >> 3;          // 0..111
  const int colt = slot % 7;          // 0..6
  const int yG = slot / 7;            // 0..15
  const int ytile = yG * 8 + xcd;     // 0..127  (same-x blocks share XCD)
  const int m0 = ytile * 128 + wid * 32;
  const int col0 = colt * 64;
  const int mt = m0 >> 5;

  // per-lane bases: step per ks = 2 kk8 = 512 u16
  const u16* abase  = X3 + (size_t)mt * 10240 + (size_t)h * 256 + r * 8;
  const u16* b0base = W3 + (size_t)(colt * 2) * 10240 + (size_t)h * 256 + r * 8;
  const u16* b1base = b0base + 10240;

  f32x16 acc0 = zero16(), acc1 = zero16();
  bf16x8 a   = *(const bf16x8*)(abase);
  bf16x8 b0v = *(const bf16x8*)(b0base);
  bf16x8 b1v = *(const bf16x8*)(b1base);
#pragma unroll 1
  for (int ks = 0; ks < 20; ++ks) {
    bf16x8 na, nb0, nb1;
    if (ks < 19) {
      na  = *(const bf16x8*)(abase  + (ks + 1) * 512);
      nb0 = *(const bf16x8*)(b0base + (ks + 1) * 512);
      nb1 = *(const bf16x8*)(b1base + (ks + 1) * 512);
    }
    acc0 = __builtin_amdgcn_mfma_f32_32x32x16_bf16(a, b0v, acc0, 0, 0, 0);
    acc1 = __builtin_amdgcn_mfma_f32_32x32x16_bf16(a, b1v, acc1, 0, 0, 0);
    a = na; b0v = nb0; b1v = nb1;
  }

  const int bb = m0 >> 11;        // batch
  const int mloc = m0 & 2047;     // n (or k) within batch

#pragma unroll
  for (int nt = 0; nt < 2; ++nt) {
    const int col = col0 + nt * 32 + r;
    const f32x16 A = nt ? acc1 : acc0;
    if (col0 >= 128) {
      // V3[b][kt8][c][8]: group g holds rows mloc + g*8 + 4h + {0..3}
      const int c = col - 128;
      const float bias = bv[c];
      u16* vdst = Vt + (((size_t)(bb * 256 + (mloc >> 3)) * 320 + c) * 8) + 4 * h;
#pragma unroll
      for (int g = 0; g < 4; ++g) {
        us4 o;
#pragma unroll
        for (int e = 0; e < 4; ++e) o[e] = f2b(A[g * 4 + e] + bias);
        *(us4*)(vdst + (size_t)g * 2560) = o;   // next kt8: +320*8
      }
    } else if (col0 >= 64) {
      const float bias = bk[col - 64];
#pragma unroll
      for (int reg = 0; reg < 16; ++reg) {
        const int row = m0 + (reg & 3) + 8 * (reg >> 2) + 4 * h;
        Kb[(size_t)row * CQ + (col - 64)] = f2b(A[reg] + bias);
      }
    } else {
      // Q3[b][kt][cq8][kl][8], pre-scaled by log2(e)
      const float bias = bq[col];
      const int kt = mloc >> 5;
      u16* qdst = Qb + (((size_t)(bb * 64 + kt) * 8 + (col >> 3)) * 32) * 8 + (col & 7);
#pragma unroll
      for (int reg = 0; reg < 16; ++reg) {
        const int kl = (reg & 3) + 8 * (reg >> 2) + 4 * h;
        qdst[kl * 8] = f2b((A[reg] + bias) * LOG2E);
      }
    }
  }
}

// ---------------------------------------------------------------------------
// K3: row sums + fold 1/S into V3. 8 waves (512 thr), grid 256 (8b x 32 kblk).
// S[k] = sum_m 2^(Q'[k]·K[m]); then V3[b][k][c] *= 1/S[k] for all c.
// ---------------------------------------------------------------------------
__global__ __launch_bounds__(512) void row_stats(
    const u16* __restrict__ Qb, const u16* __restrict__ Kb,
    u16* __restrict__ Vt) {
  __shared__ float Sp[8][64];
  __shared__ float sInv[64];
  const int tid = threadIdx.x;
  const int lane = tid & 63, wid = tid >> 6;   // 0..7
  const int rl = lane & 15, hq = lane >> 4;
  const int bid = blockIdx.x;
  const int batch = bid & 7;
  const int kloc64 = (bid >> 3) * 64;          // bid>>3 in [0,32)

  // A-frags from Q3: rows kloc64 + mt*16 + rl, cq = qs*32 + hq*8
  bf16x8 af[4][2];
#pragma unroll
  for (int mt = 0; mt < 4; ++mt) {
    const int k_loc = kloc64 + mt * 16 + rl;
    const int kt = k_loc >> 5, kl = k_loc & 31;
#pragma unroll
    for (int qs = 0; qs < 2; ++qs)
      af[mt][qs] = *(const bf16x8*)(Qb +
          (((size_t)(batch * 64 + kt) * 8 + qs * 4 + hq) * 32 + kl) * 8);
  }

  float S[4][4];
#pragma unroll
  for (int mt = 0; mt < 4; ++mt)
#pragma unroll
    for (int rr = 0; rr < 4; ++rr) S[mt][rr] = 0.f;

  const int mstart = batch * NN + wid * 256;
  const u16* kr = Kb + (size_t)(mstart + rl) * CQ + hq * 8;
  bf16x8 c0 = *(const bf16x8*)(kr);
  bf16x8 c1 = *(const bf16x8*)(kr + 32);
#pragma unroll 1
  for (int ms = 0; ms < 16; ++ms) {
    bf16x8 n0, n1;
    if (ms < 15) {
      n0 = *(const bf16x8*)(kr + 16 * CQ);
      n1 = *(const bf16x8*)(kr + 16 * CQ + 32);
    }
#pragma unroll
    for (int mt = 0; mt < 4; ++mt) {
      f32x4 e = zero4();
      e = __builtin_amdgcn_mfma_f32_16x16x32_bf16(af[mt][0], c0, e, 0, 0, 0);
      e = __builtin_amdgcn_mfma_f32_16x16x32_bf16(af[mt][1], c1, e, 0, 0, 0);
#pragma unroll
      for (int rr = 0; rr < 4; ++rr) S[mt][rr] += __builtin_amdgcn_exp2f(e[rr]);
    }
    c0 = n0; c1 = n1; kr += 16 * CQ;
  }

#pragma unroll
  for (int d = 1; d < 16; d <<= 1)
#pragma unroll
    for (int mt = 0; mt < 4; ++mt)
#pragma unroll
      for (int rr = 0; rr < 4; ++rr) S[mt][rr] += __shfl_xor(S[mt][rr], d, 64);

  if (rl == 0) {
#pragma unroll
    for (int mt = 0; mt < 4; ++mt)
#pragma unroll
      for (int rr = 0; rr < 4; ++rr) Sp[wid][mt * 16 + hq * 4 + rr] = S[mt][rr];
  }
  __syncthreads();
  if (tid < 64) {
    float s = 0.f;
#pragma unroll
    for (int p = 0; p < 8; ++p) s += Sp[p][tid];
    sInv[tid] = 1.0f / s;
  }
  __syncthreads();

  // scale V3[b][kt8b..kt8b+8)[c][8] by sInv — fully coalesced us4 stream
  const int kt8b = kloc64 >> 3;
#pragma unroll 1
  for (int i = 0; i < 10; ++i) {
    const int chunk = i * 512 + tid;     // 0..5119
    const int kt8l = chunk / 640;        // 0..7
    const int rem = chunk - kt8l * 640;  // 0..639
    const int c = rem >> 1;
    const int h2 = rem & 1;
    u16* p = Vt + (((size_t)(batch * 256 + kt8b + kt8l) * 320 + c) * 8) + h2 * 4;
    us4 v = *(const us4*)p;
    us4 o;
#pragma unroll
    for (int e2 = 0; e2 < 4; ++e2) o[e2] = f2b(b2f(v[e2]) * sInv[kt8l * 8 + h2 * 4 + e2]);
    *(us4*)p = o;
  }
}

// ---------------------------------------------------------------------------
// K4: attention v7 (passing) — LDS-staged, paired waves.
// Block = 256 thr = 4 waves: (wn = n-tile 0/1) x (kh = k-half 0/1).
// Grid 512 = 8b x 2ch x 32 n-pairs. Per k-tile (32k) the block stages ONCE
// via global_load_lds: Q(4KB) + V(10KB) per kh = 28KB, double-buffered.
// Residual reads x (fp32) directly. batch = bid&7 (XCD-pinned).
// ---------------------------------------------------------------------------
__global__ __launch_bounds__(256, 2) void attn(
    const u16* __restrict__ Qb, const u16* __restrict__ Kb,
    const u16* __restrict__ Vt, const float* __restrict__ x,
    const float* __restrict__ gamma, float* __restrict__ out) {
  __shared__ __align__(16) char LDSRAW[57344];   // 2 bufs x 2 kh x 14336
  const int tid = threadIdx.x;
  const int lane = tid & 63, wid = tid >> 6;
  const int wn = wid >> 1;       // n-tile within pair
  const int kh = wid & 1;        // k-half
  const int r = lane & 31, h = lane >> 5;
  const int bid = blockIdx.x;
  const int b = bid & 7;
  const int rest = bid >> 3;
  const int ch = rest & 1;
  const int n0 = (rest >> 1) * 64;

  // K fragments for n-tile n0 + wn*32 (held all k)
  bf16x8 kf[4];
  {
    const u16* krow = Kb + (size_t)(b * NN + n0 + wn * 32 + r) * CQ + h * 8;
#pragma unroll
    for (int qs = 0; qs < 4; ++qs) kf[qs] = *(const bf16x8*)(krow + qs * 16);
  }

  f32x16 acc[5];
#pragma unroll
  for (int j = 0; j < 5; ++j) acc[j] = zero16();

  // stage: 28 chunks of 1KB (4 Q + 10 V per kh), wave w takes [w*7, w*7+7)
#define STAGE(TN, BUF) {                                                       \
    _Pragma("unroll")                                                          \
    for (int i_ = 0; i_ < 7; ++i_) {                                           \
      const int c_ = wid * 7 + i_;                                             \
      const int khc_ = c_ / 14;                                                \
      const int rem_ = c_ % 14;                                                \
      char* dst_ = LDSRAW + (BUF) * 28672 + khc_ * 14336 + rem_ * 1024;        \
      if (rem_ < 4) {                                                          \
        const u16* src_ = Qb + ((size_t)(b * 64 + khc_ * 32 + (TN)) * 2048)    \
                             + rem_ * 512 + lane * 8;                          \
        gll16(src_, dst_);                                                     \
      } else {                                                                 \
        const int v_ = rem_ - 4;                                               \
        const int off_ = v_ * 512 + lane * 8;                                  \
        const int row_ = off_ / 1280;                                          \
        const int win_ = off_ - row_ * 1280;                                   \
        const u16* src_ = Vt +                                                 \
            ((size_t)(b * 256 + khc_ * 128 + (TN) * 4 + row_) * 320            \
             + ch * 160) * 8 + win_;                                           \
        gll16(src_, dst_);                                                     \
      }                                                                        \
    }                                                                          \
  }

#define COMPUTE(T) {                                                           \
    const char* base_ = LDSRAW + ((T) & 1) * 28672 + kh * 14336;               \
    bf16x8 qf[4];                                                              \
    _Pragma("unroll")                                                          \
    for (int qs = 0; qs < 4; ++qs)                                             \
      qf[qs] = *(const bf16x8*)(base_ + (qs * 2 + h) * 512 + r * 16);          \
    f32x16 e = zero16();                                                       \
    _Pragma("unroll")                                                          \
    for (int qs = 0; qs < 4; ++qs)                                             \
      e = __builtin_amdgcn_mfma_f32_32x32x16_bf16(qf[qs], kf[qs], e, 0, 0, 0); \
    bf16x8 vf[5][2];                                                           \
    _Pragma("unroll")                                                          \
    for (int j = 0; j < 5; ++j)                                                \
      _Pragma("unroll")                                                        \
      for (int ks = 0; ks < 2; ++ks)                                           \
        vf[j][ks] = *(const bf16x8*)(base_ + 4096 + (ks * 2 + h) * 2560        \
                                     + (j * 32 + r) * 16);                     \
    unsigned pk0, pk1, pk2, pk3, pk4, pk5, pk6, pk7;                           \
    { float l0 = __builtin_amdgcn_exp2f(e[0]),  h0 = __builtin_amdgcn_exp2f(e[1]);  \
      float l1 = __builtin_amdgcn_exp2f(e[2]),  h1 = __builtin_amdgcn_exp2f(e[3]);  \
      float l2 = __builtin_amdgcn_exp2f(e[4]),  h2 = __builtin_amdgcn_exp2f(e[5]);  \
      float l3 = __builtin_amdgcn_exp2f(e[6]),  h3 = __builtin_amdgcn_exp2f(e[7]);  \
      float l4 = __builtin_amdgcn_exp2f(e[8]),  h4 = __builtin_amdgcn_exp2f(e[9]);  \
      float l5 = __builtin_amdgcn_exp2f(e[10]), h5 = __builtin_amdgcn_exp2f(e[11]); \
      float l6 = __builtin_amdgcn_exp2f(e[12]), h6 = __builtin_amdgcn_exp2f(e[13]); \
      float l7 = __builtin_amdgcn_exp2f(e[14]), h7 = __builtin_amdgcn_exp2f(e[15]); \
      asm("v_cvt_pk_bf16_f32 %0, %1, %2" : "=v"(pk0) : "v"(l0), "v"(h0));      \
      asm("v_cvt_pk_bf16_f32 %0, %1, %2" : "=v"(pk1) : "v"(l1), "v"(h1));      \
      asm("v_cvt_pk_bf16_f32 %0, %1, %2" : "=v"(pk2) : "v"(l2), "v"(h2));      \
      asm("v_cvt_pk_bf16_f32 %0, %1, %2" : "=v"(pk3) : "v"(l3), "v"(h3));      \
      asm("v_cvt_pk_bf16_f32 %0, %1, %2" : "=v"(pk4) : "v"(l4), "v"(h4));      \
      asm("v_cvt_pk_bf16_f32 %0, %1, %2" : "=v"(pk5) : "v"(l5), "v"(h5));      \
      asm("v_cvt_pk_bf16_f32 %0, %1, %2" : "=v"(pk6) : "v"(l6), "v"(h6));      \
      asm("v_cvt_pk_bf16_f32 %0, %1, %2" : "=v"(pk7) : "v"(l7), "v"(h7)); }    \
    asm("v_permlane32_swap_b32 %0, %1" : "+v"(pk0), "+v"(pk2));                \
    asm("v_permlane32_swap_b32 %0, %1" : "+v"(pk1), "+v"(pk3));                \
    asm("v_permlane32_swap_b32 %0, %1" : "+v"(pk4), "+v"(pk6));                \
    asm("v_permlane32_swap_b32 %0, %1" : "+v"(pk5), "+v"(pk7));                \
    u32x4 w0_ = {pk0, pk1, pk2, pk3};                                          \
    u32x4 w1_ = {pk4, pk5, pk6, pk7};                                          \
    bf16x8 pa0 = __builtin_bit_cast(bf16x8, w0_);                              \
    bf16x8 pa1 = __builtin_bit_cast(bf16x8, w1_);                              \
    _Pragma("unroll")                                                          \
    for (int j = 0; j < 5; ++j) {                                              \
      acc[j] = __builtin_amdgcn_mfma_f32_32x32x16_bf16(pa0, vf[j][0], acc[j], 0, 0, 0); \
      acc[j] = __builtin_amdgcn_mfma_f32_32x32x16_bf16(pa1, vf[j][1], acc[j], 0, 0, 0); \
    }                                                                          \
  }

  STAGE(0, 0);
  __syncthreads();
#pragma unroll 1
  for (int t = 0; t < 32; ++t) {
    if (t < 31) STAGE(t + 1, (t + 1) & 1);
    COMPUTE(t);
    __syncthreads();
  }
#undef STAGE
#undef COMPUTE

  // kh=1 waves dump partial sums; kh=0 waves combine and write out
  float* red = (float*)LDSRAW;   // 2 regions x 5120 f32 = 40 KB
  if (kh == 1) {
#pragma unroll
    for (int reg = 0; reg < 16; ++reg) {
      const int nl = (reg & 3) + 8 * (reg >> 2) + 4 * h;
#pragma unroll
      for (int j = 0; j < 5; ++j)
        red[wn * 5120 + nl * 160 + j * 32 + r] = acc[j][reg];
    }
  }
  __syncthreads();
  if (kh == 0) {
    const float g = gamma[0];
#pragma unroll
    for (int reg = 0; reg < 16; ++reg) {
      const int nl = (reg & 3) + 8 * (reg >> 2) + 4 * h;
      const size_t rowb = ((size_t)(b * NN) + n0 + wn * 32 + nl) * CC + ch * 160 + r;
#pragma unroll
      for (int j = 0; j < 5; ++j) {
        const size_t idx = rowb + (size_t)(j * 32);
        const float s = acc[j][reg] + red[wn * 5120 + nl * 160 + j * 32 + r];
        out[idx] = g * s + x[idx];
      }
    }
  }
}

extern "C" void kernel_launch(void* const* d_in, const int* in_sizes, int n_in,
                              void* d_out, int out_size, void* d_ws, size_t ws_size,
                              hipStream_t stream) {
  const float* x     = (const float*)d_in[0];
  const float* Wq    = (const float*)d_in[1];
  const float* bq    = (const float*)d_in[2];
  const float* Wk    = (const float*)d_in[3];
  const float* bk    = (const float*)d_in[4];
  const float* Wv    = (const float*)d_in[5];
  const float* bv    = (const float*)d_in[6];
  const float* gamma = (const float*)d_in[7];
  float* out = (float*)d_out;

  char* w = (char*)d_ws;
  u16* X3 = (u16*)(w);                         // 512*40*32*8 (10485760 B)
  u16* W3 = (u16*)(w + 10485760);              // 14*40*32*8  (286720 B)
  u16* Qb = (u16*)(w + 10772480);              // Q3: 8*64*8*32*8 (2097152 B)
  u16* Kb = (u16*)(w + 12869632);              // 16384*64    (2097152 B)
  u16* Vt = (u16*)(w + 14966784);              // V3: 8*256*320*8 (10485760 B)

  cvt_x_blk<<<512, 256, 0, stream>>>(x, X3);
  cvt_w_blk<<<14, 256, 0, stream>>>(Wq, Wk, Wv, W3);
  gemm_qkv<<<896, 256, 0, stream>>>(X3, W3, bq, bk, bv, Qb, Kb, Vt);
  row_stats<<<256, 512, 0, stream>>>(Qb, Kb, Vt);
  attn<<<512, 256, 0, stream>>>(Qb, Kb, Vt, x, gamma, out);
}

// Round 14
// 87.107 us; speedup vs baseline: 1.3532x; 1.0409x over previous
//
#include <hip/hip_runtime.h>
#include <hip/hip_bf16.h>

#define BB 8
#define NN 2048
#define CC 320
#define CQ 64
#define LOG2E 1.4426950408889634f

typedef __attribute__((ext_vector_type(8)))  short bf16x8;
typedef __attribute__((ext_vector_type(4)))  float f32x4;
typedef __attribute__((ext_vector_type(16))) float f32x16;
typedef __attribute__((ext_vector_type(4)))  unsigned short us4;
typedef __attribute__((ext_vector_type(8)))  unsigned short us8;
typedef __attribute__((ext_vector_type(4)))  unsigned int u32x4;
typedef unsigned short u16;

// Layouts:
//  X3[mt=m/32][kk8=k/8][ml=m%32][8]       (bf16; lane-contiguous A-frags)
//  W3[ct=c/32][kk8=k/8][cl=c%32][8]       (bf16; lane-contiguous B-frags)
//  Q3[b][kt=k/32][cq8=cq/8][kl=k%32][8]   (bf16, pre-scaled by log2e)
//  Kb[b*N+n][cq]                          (row-major)
//  V3[b][kt8=k/8][c][8]                   (bf16, scaled by 1/S[k] in K3)

static __device__ __forceinline__ u16 f2b(float f) {
  unsigned u = __builtin_bit_cast(unsigned, f);
  unsigned r = (u + 0x7FFFu + ((u >> 16) & 1u)) >> 16;
  return (u16)r;
}
static __device__ __forceinline__ float b2f(u16 s) {
  unsigned u = ((unsigned)s) << 16;
  return __builtin_bit_cast(float, u);
}

static __device__ __forceinline__ f32x16 zero16() {
  f32x16 v = {0,0,0,0, 0,0,0,0, 0,0,0,0, 0,0,0,0};
  return v;
}
static __device__ __forceinline__ f32x4 zero4() {
  f32x4 v = {0,0,0,0};
  return v;
}

static __device__ __forceinline__ void gll16(const void* g, void* l) {
  __builtin_amdgcn_global_load_lds(
      (const __attribute__((address_space(1))) unsigned int*)g,
      (__attribute__((address_space(3))) unsigned int*)l, 16, 0, 0);
}

// 8 fp32 -> bf16x8 via hardware packed converts (RNE, same as f2b)
static __device__ __forceinline__ bf16x8 cvt8(float4 a, float4 b) {
  unsigned p0, p1, p2, p3;
  asm("v_cvt_pk_bf16_f32 %0, %1, %2" : "=v"(p0) : "v"(a.x), "v"(a.y));
  asm("v_cvt_pk_bf16_f32 %0, %1, %2" : "=v"(p1) : "v"(a.z), "v"(a.w));
  asm("v_cvt_pk_bf16_f32 %0, %1, %2" : "=v"(p2) : "v"(b.x), "v"(b.y));
  asm("v_cvt_pk_bf16_f32 %0, %1, %2" : "=v"(p3) : "v"(b.z), "v"(b.w));
  u32x4 w = {p0, p1, p2, p3};
  return __builtin_bit_cast(bf16x8, w);
}

// ---------------------------------------------------------------------------
// K0a: x fp32 -> X3 blocked bf16 via LDS transpose. grid 512 x 256.
// ---------------------------------------------------------------------------
__global__ __launch_bounds__(256) void cvt_x_blk(const float* __restrict__ x,
                                                 u16* __restrict__ X3) {
  __shared__ float xs[32][324];   // +4 pad: conflict-free transpose reads
  const int t = threadIdx.x;
  const int b = blockIdx.x;
  const size_t srcb = (size_t)b * 32 * CC;
#pragma unroll
  for (int i = 0; i < 10; ++i) {
    const int lidx = i * 256 + t;        // 0..2559 float4 units
    const int m = lidx / 80;             // 80 float4 per row
    const int kq = lidx - m * 80;
    float4 v = *(const float4*)(x + srcb + (size_t)m * CC + kq * 4);
    *(float4*)&xs[m][kq * 4] = v;
  }
  __syncthreads();
  u16* dst0 = X3 + (size_t)b * 10240;    // 40*256
#pragma unroll
  for (int i = 0; i < 5; ++i) {
    const int u = i * 256 + t;           // 0..1279: kk8*32 + ml
    const int kk8 = u >> 5, ml = u & 31;
    float4 a = *(const float4*)&xs[ml][kk8 * 8];
    float4 c = *(const float4*)&xs[ml][kk8 * 8 + 4];
    bf16x8 o = cvt8(a, c);
    *(bf16x8*)(dst0 + (size_t)u * 8) = o;
  }
}

// ---------------------------------------------------------------------------
// K0b: Wq/Wk/Wv fp32 -> W3 blocked bf16. grid 14 x 256.
// ---------------------------------------------------------------------------
__global__ __launch_bounds__(256) void cvt_w_blk(const float* __restrict__ Wq,
                                                 const float* __restrict__ Wk,
                                                 const float* __restrict__ Wv,
                                                 u16* __restrict__ W3) {
  __shared__ float xs[32][324];
  const int t = threadIdx.x;
  const int b = blockIdx.x;
#pragma unroll
  for (int i = 0; i < 10; ++i) {
    const int lidx = i * 256 + t;
    const int m = lidx / 80;
    const int kq = lidx - m * 80;
    const int row = b * 32 + m;
    const float* src = (row < 64) ? (Wq + (size_t)row * CC)
                     : (row < 128) ? (Wk + (size_t)(row - 64) * CC)
                                   : (Wv + (size_t)(row - 128) * CC);
    float4 v = *(const float4*)(src + kq * 4);
    *(float4*)&xs[m][kq * 4] = v;
  }
  __syncthreads();
  u16* dst0 = W3 + (size_t)b * 10240;
#pragma unroll
  for (int i = 0; i < 5; ++i) {
    const int u = i * 256 + t;
    const int kk8 = u >> 5, ml = u & 31;
    float4 a = *(const float4*)&xs[ml][kk8 * 8];
    float4 c = *(const float4*)&xs[ml][kk8 * 8 + 4];
    bf16x8 o = cvt8(a, c);
    *(bf16x8*)(dst0 + (size_t)u * 8) = o;
  }
}

// ---------------------------------------------------------------------------
// K1: QKV GEMM from blocked X3/W3 (8-line requests), XCD-aware remap.
// grid 896 x 256.
// ---------------------------------------------------------------------------
__global__ __launch_bounds__(256) void gemm_qkv(
    const u16* __restrict__ X3, const u16* __restrict__ W3,
    const float* __restrict__ bq, const float* __restrict__ bk,
    const float* __restrict__ bv,
    u16* __restrict__ Qb, u16* __restrict__ Kb, u16* __restrict__ Vt) {
  const int tid = threadIdx.x;
  const int lane = tid & 63, wid = tid >> 6;
  const int r = lane & 31, h = lane >> 5;
  const int bid = blockIdx.x;
  const int xcd = bid & 7;
  const int slot = bid >> 3;          // 0..111
  const int colt = slot % 7;          // 0..6
  const int yG = slot / 7;            // 0..15
  const int ytile = yG * 8 + xcd;     // 0..127
  const int m0 = ytile * 128 + wid * 32;
  const int col0 = colt * 64;
  const int mt = m0 >> 5;

  const u16* abase  = X3 + (size_t)mt * 10240 + (size_t)h * 256 + r * 8;
  const u16* b0base = W3 + (size_t)(colt * 2) * 10240 + (size_t)h * 256 + r * 8;
  const u16* b1base = b0base + 10240;

  f32x16 acc0 = zero16(), acc1 = zero16();
  bf16x8 a   = *(const bf16x8*)(abase);
  bf16x8 b0v = *(const bf16x8*)(b0base);
  bf16x8 b1v = *(const bf16x8*)(b1base);
#pragma unroll 1
  for (int ks = 0; ks < 20; ++ks) {
    bf16x8 na, nb0, nb1;
    if (ks < 19) {
      na  = *(const bf16x8*)(abase  + (ks + 1) * 512);
      nb0 = *(const bf16x8*)(b0base + (ks + 1) * 512);
      nb1 = *(const bf16x8*)(b1base + (ks + 1) * 512);
    }
    acc0 = __builtin_amdgcn_mfma_f32_32x32x16_bf16(a, b0v, acc0, 0, 0, 0);
    acc1 = __builtin_amdgcn_mfma_f32_32x32x16_bf16(a, b1v, acc1, 0, 0, 0);
    a = na; b0v = nb0; b1v = nb1;
  }

  const int bb = m0 >> 11;        // batch
  const int mloc = m0 & 2047;     // n (or k) within batch

#pragma unroll
  for (int nt = 0; nt < 2; ++nt) {
    const int col = col0 + nt * 32 + r;
    const f32x16 A = nt ? acc1 : acc0;
    if (col0 >= 128) {
      const int c = col - 128;
      const float bias = bv[c];
      u16* vdst = Vt + (((size_t)(bb * 256 + (mloc >> 3)) * 320 + c) * 8) + 4 * h;
#pragma unroll
      for (int g = 0; g < 4; ++g) {
        us4 o;
#pragma unroll
        for (int e = 0; e < 4; ++e) o[e] = f2b(A[g * 4 + e] + bias);
        *(us4*)(vdst + (size_t)g * 2560) = o;
      }
    } else if (col0 >= 64) {
      const float bias = bk[col - 64];
#pragma unroll
      for (int reg = 0; reg < 16; ++reg) {
        const int row = m0 + (reg & 3) + 8 * (reg >> 2) + 4 * h;
        Kb[(size_t)row * CQ + (col - 64)] = f2b(A[reg] + bias);
      }
    } else {
      const float bias = bq[col];
      const int kt = mloc >> 5;
      u16* qdst = Qb + (((size_t)(bb * 64 + kt) * 8 + (col >> 3)) * 32) * 8 + (col & 7);
#pragma unroll
      for (int reg = 0; reg < 16; ++reg) {
        const int kl = (reg & 3) + 8 * (reg >> 2) + 4 * h;
        qdst[kl * 8] = f2b((A[reg] + bias) * LOG2E);
      }
    }
  }
}

// ---------------------------------------------------------------------------
// K3: row sums + fold 1/S into V3. 8 waves (512 thr), grid 256 (8b x 32 kblk).
// ---------------------------------------------------------------------------
__global__ __launch_bounds__(512) void row_stats(
    const u16* __restrict__ Qb, const u16* __restrict__ Kb,
    u16* __restrict__ Vt) {
  __shared__ float Sp[8][64];
  __shared__ float sInv[64];
  const int tid = threadIdx.x;
  const int lane = tid & 63, wid = tid >> 6;   // 0..7
  const int rl = lane & 15, hq = lane >> 4;
  const int bid = blockIdx.x;
  const int batch = bid & 7;
  const int kloc64 = (bid >> 3) * 64;          // bid>>3 in [0,32)

  bf16x8 af[4][2];
#pragma unroll
  for (int mt = 0; mt < 4; ++mt) {
    const int k_loc = kloc64 + mt * 16 + rl;
    const int kt = k_loc >> 5, kl = k_loc & 31;
#pragma unroll
    for (int qs = 0; qs < 2; ++qs)
      af[mt][qs] = *(const bf16x8*)(Qb +
          (((size_t)(batch * 64 + kt) * 8 + qs * 4 + hq) * 32 + kl) * 8);
  }

  float S[4][4];
#pragma unroll
  for (int mt = 0; mt < 4; ++mt)
#pragma unroll
    for (int rr = 0; rr < 4; ++rr) S[mt][rr] = 0.f;

  const int mstart = batch * NN + wid * 256;
  const u16* kr = Kb + (size_t)(mstart + rl) * CQ + hq * 8;
  bf16x8 c0 = *(const bf16x8*)(kr);
  bf16x8 c1 = *(const bf16x8*)(kr + 32);
#pragma unroll 1
  for (int ms = 0; ms < 16; ++ms) {
    bf16x8 n0, n1;
    if (ms < 15) {
      n0 = *(const bf16x8*)(kr + 16 * CQ);
      n1 = *(const bf16x8*)(kr + 16 * CQ + 32);
    }
#pragma unroll
    for (int mt = 0; mt < 4; ++mt) {
      f32x4 e = zero4();
      e = __builtin_amdgcn_mfma_f32_16x16x32_bf16(af[mt][0], c0, e, 0, 0, 0);
      e = __builtin_amdgcn_mfma_f32_16x16x32_bf16(af[mt][1], c1, e, 0, 0, 0);
#pragma unroll
      for (int rr = 0; rr < 4; ++rr) S[mt][rr] += __builtin_amdgcn_exp2f(e[rr]);
    }
    c0 = n0; c1 = n1; kr += 16 * CQ;
  }

#pragma unroll
  for (int d = 1; d < 16; d <<= 1)
#pragma unroll
    for (int mt = 0; mt < 4; ++mt)
#pragma unroll
      for (int rr = 0; rr < 4; ++rr) S[mt][rr] += __shfl_xor(S[mt][rr], d, 64);

  if (rl == 0) {
#pragma unroll
    for (int mt = 0; mt < 4; ++mt)
#pragma unroll
      for (int rr = 0; rr < 4; ++rr) Sp[wid][mt * 16 + hq * 4 + rr] = S[mt][rr];
  }
  __syncthreads();
  if (tid < 64) {
    float s = 0.f;
#pragma unroll
    for (int p = 0; p < 8; ++p) s += Sp[p][tid];
    sInv[tid] = 1.0f / s;
  }
  __syncthreads();

  const int kt8b = kloc64 >> 3;
#pragma unroll 1
  for (int i = 0; i < 10; ++i) {
    const int chunk = i * 512 + tid;     // 0..5119
    const int kt8l = chunk / 640;        // 0..7
    const int rem = chunk - kt8l * 640;  // 0..639
    const int c = rem >> 1;
    const int h2 = rem & 1;
    u16* p = Vt + (((size_t)(batch * 256 + kt8b + kt8l) * 320 + c) * 8) + h2 * 4;
    us4 v = *(const us4*)p;
    us4 o;
#pragma unroll
    for (int e2 = 0; e2 < 4; ++e2) o[e2] = f2b(b2f(v[e2]) * sInv[kt8l * 8 + h2 * 4 + e2]);
    *(us4*)p = o;
  }
}

// ---------------------------------------------------------------------------
// K4: attention v9 — V-only LDS staging, Q direct-from-global with named
// A/B register prefetch (one tile ahead). Same barrier skeleton as the
// passing v7: STAGE(t+1) -> COMPUTE(t) -> barrier. LDS 40 KB (was 56).
// Block = 256 thr = 4 waves: (wn n-tile 0/1) x (kh k-half 0/1).
// Grid 512 = 8b x 2ch x 32 n-pairs; batch = bid&7 (XCD-pinned).
// ---------------------------------------------------------------------------
__global__ __launch_bounds__(256, 2) void attn(
    const u16* __restrict__ Qb, const u16* __restrict__ Kb,
    const u16* __restrict__ Vt, const float* __restrict__ x,
    const float* __restrict__ gamma, float* __restrict__ out) {
  __shared__ __align__(16) char LDSRAW[40960];   // 2 bufs x 2 kh x 10240 (V)
  const int tid = threadIdx.x;
  const int lane = tid & 63, wid = tid >> 6;
  const int wn = wid >> 1;       // n-tile within pair
  const int kh = wid & 1;        // k-half
  const int r = lane & 31, h = lane >> 5;
  const int bid = blockIdx.x;
  const int b = bid & 7;
  const int rest = bid >> 3;
  const int ch = rest & 1;
  const int n0 = (rest >> 1) * 64;

  // K fragments for n-tile n0 + wn*32 (held all k)
  bf16x8 kf[4];
  {
    const u16* krow = Kb + (size_t)(b * NN + n0 + wn * 32 + r) * CQ + h * 8;
#pragma unroll
    for (int qs = 0; qs < 4; ++qs) kf[qs] = *(const bf16x8*)(krow + qs * 16);
  }

  f32x16 acc[5];
#pragma unroll
  for (int j = 0; j < 5; ++j) acc[j] = zero16();

  // Q3 per-lane base for this wave's k-half: kt = kh*32 + T
  const u16* qb3 = Qb + ((size_t)(b * 64 + kh * 32) * 8) * 256 + (size_t)r * 8;

  // stage V only: 20 chunks of 1KB (10 per kh), wave w takes [w*5, w*5+5)
#define STAGE(TN, BUF) {                                                       \
    _Pragma("unroll")                                                          \
    for (int i_ = 0; i_ < 5; ++i_) {                                           \
      const int c_ = wid * 5 + i_;                                             \
      const int khc_ = c_ / 10;                                                \
      const int rem_ = c_ % 10;                                                \
      char* dst_ = LDSRAW + (BUF) * 20480 + khc_ * 10240 + rem_ * 1024;        \
      const int off_ = rem_ * 512 + lane * 8;                                  \
      const int row_ = off_ / 1280;                                            \
      const int win_ = off_ - row_ * 1280;                                     \
      const u16* src_ = Vt +                                                   \
          ((size_t)(b * 256 + khc_ * 128 + (TN) * 4 + row_) * 320              \
           + ch * 160) * 8 + win_;                                             \
      gll16(src_, dst_);                                                       \
    }                                                                          \
  }

// prefetch Q frags for tile TN into QN (plain global loads, lane-contiguous)
#define LQ(QN, TN) {                                                           \
    _Pragma("unroll")                                                          \
    for (int qs = 0; qs < 4; ++qs)                                             \
      QN[qs] = *(const bf16x8*)(qb3 + ((size_t)(TN) * 8 + qs * 2 + h) * 256);  \
  }

// compute tile T from LDS buffer BUF using prefetched QF; prefetch QN for TNX
#define COMPUTE(T, BUF, QF, QN, TNX) {                                         \
    LQ(QN, TNX)                                                                \
    const char* base_ = LDSRAW + (BUF) * 20480 + kh * 10240;                   \
    f32x16 e = zero16();                                                       \
    _Pragma("unroll")                                                          \
    for (int qs = 0; qs < 4; ++qs)                                             \
      e = __builtin_amdgcn_mfma_f32_32x32x16_bf16(QF[qs], kf[qs], e, 0, 0, 0); \
    bf16x8 vf[5][2];                                                           \
    _Pragma("unroll")                                                          \
    for (int j = 0; j < 5; ++j)                                                \
      _Pragma("unroll")                                                        \
      for (int ks = 0; ks < 2; ++ks)                                           \
        vf[j][ks] = *(const bf16x8*)(base_ + (ks * 2 + h) * 2560               \
                                     + (j * 32 + r) * 16);                     \
    unsigned pk0, pk1, pk2, pk3, pk4, pk5, pk6, pk7;                           \
    { float l0 = __builtin_amdgcn_exp2f(e[0]),  h0 = __builtin_amdgcn_exp2f(e[1]);  \
      float l1 = __builtin_amdgcn_exp2f(e[2]),  h1 = __builtin_amdgcn_exp2f(e[3]);  \
      float l2 = __builtin_amdgcn_exp2f(e[4]),  h2 = __builtin_amdgcn_exp2f(e[5]);  \
      float l3 = __builtin_amdgcn_exp2f(e[6]),  h3 = __builtin_amdgcn_exp2f(e[7]);  \
      float l4 = __builtin_amdgcn_exp2f(e[8]),  h4 = __builtin_amdgcn_exp2f(e[9]);  \
      float l5 = __builtin_amdgcn_exp2f(e[10]), h5 = __builtin_amdgcn_exp2f(e[11]); \
      float l6 = __builtin_amdgcn_exp2f(e[12]), h6 = __builtin_amdgcn_exp2f(e[13]); \
      float l7 = __builtin_amdgcn_exp2f(e[14]), h7 = __builtin_amdgcn_exp2f(e[15]); \
      asm("v_cvt_pk_bf16_f32 %0, %1, %2" : "=v"(pk0) : "v"(l0), "v"(h0));      \
      asm("v_cvt_pk_bf16_f32 %0, %1, %2" : "=v"(pk1) : "v"(l1), "v"(h1));      \
      asm("v_cvt_pk_bf16_f32 %0, %1, %2" : "=v"(pk2) : "v"(l2), "v"(h2));      \
      asm("v_cvt_pk_bf16_f32 %0, %1, %2" : "=v"(pk3) : "v"(l3), "v"(h3));      \
      asm("v_cvt_pk_bf16_f32 %0, %1, %2" : "=v"(pk4) : "v"(l4), "v"(h4));      \
      asm("v_cvt_pk_bf16_f32 %0, %1, %2" : "=v"(pk5) : "v"(l5), "v"(h5));      \
      asm("v_cvt_pk_bf16_f32 %0, %1, %2" : "=v"(pk6) : "v"(l6), "v"(h6));      \
      asm("v_cvt_pk_bf16_f32 %0, %1, %2" : "=v"(pk7) : "v"(l7), "v"(h7)); }    \
    asm("v_permlane32_swap_b32 %0, %1" : "+v"(pk0), "+v"(pk2));                \
    asm("v_permlane32_swap_b32 %0, %1" : "+v"(pk1), "+v"(pk3));                \
    asm("v_permlane32_swap_b32 %0, %1" : "+v"(pk4), "+v"(pk6));                \
    asm("v_permlane32_swap_b32 %0, %1" : "+v"(pk5), "+v"(pk7));                \
    u32x4 w0_ = {pk0, pk1, pk2, pk3};                                          \
    u32x4 w1_ = {pk4, pk5, pk6, pk7};                                          \
    bf16x8 pa0 = __builtin_bit_cast(bf16x8, w0_);                              \
    bf16x8 pa1 = __builtin_bit_cast(bf16x8, w1_);                              \
    _Pragma("unroll")                                                          \
    for (int j = 0; j < 5; ++j) {                                              \
      acc[j] = __builtin_amdgcn_mfma_f32_32x32x16_bf16(pa0, vf[j][0], acc[j], 0, 0, 0); \
      acc[j] = __builtin_amdgcn_mfma_f32_32x32x16_bf16(pa1, vf[j][1], acc[j], 0, 0, 0); \
    }                                                                          \
  }

  bf16x8 qfA[4], qfB[4];

  STAGE(0, 0);
  LQ(qfA, 0)
  __syncthreads();
#pragma unroll 1
  for (int t = 0; t < 32; t += 2) {
    STAGE(t + 1, 1);                          // odd tile -> buf1
    COMPUTE(t, 0, qfA, qfB, t + 1);           // even tile from buf0; prefetch Q(t+1)
    __syncthreads();
    if (t + 2 < 32) STAGE(t + 2, 0);          // even tile -> buf0
    COMPUTE(t + 1, 1, qfB, qfA, (t + 2) & 31);// odd tile from buf1; prefetch Q(t+2)
    __syncthreads();
  }
#undef STAGE
#undef LQ
#undef COMPUTE

  // kh=1 waves dump partial sums; kh=0 waves combine and write out
  float* red = (float*)LDSRAW;   // 2 regions x 5120 f32 = 40960 B (fits)
  if (kh == 1) {
#pragma unroll
    for (int reg = 0; reg < 16; ++reg) {
      const int nl = (reg & 3) + 8 * (reg >> 2) + 4 * h;
#pragma unroll
      for (int j = 0; j < 5; ++j)
        red[wn * 5120 + nl * 160 + j * 32 + r] = acc[j][reg];
    }
  }
  __syncthreads();
  if (kh == 0) {
    const float g = gamma[0];
#pragma unroll
    for (int reg = 0; reg < 16; ++reg) {
      const int nl = (reg & 3) + 8 * (reg >> 2) + 4 * h;
      const size_t rowb = ((size_t)(b * NN) + n0 + wn * 32 + nl) * CC + ch * 160 + r;
#pragma unroll
      for (int j = 0; j < 5; ++j) {
        const size_t idx = rowb + (size_t)(j * 32);
        const float s = acc[j][reg] + red[wn * 5120 + nl * 160 + j * 32 + r];
        out[idx] = g * s + x[idx];
      }
    }
  }
}

extern "C" void kernel_launch(void* const* d_in, const int* in_sizes, int n_in,
                              void* d_out, int out_size, void* d_ws, size_t ws_size,
                              hipStream_t stream) {
  const float* x     = (const float*)d_in[0];
  const float* Wq    = (const float*)d_in[1];
  const float* bq    = (const float*)d_in[2];
  const float* Wk    = (const float*)d_in[3];
  const float* bk    = (const float*)d_in[4];
  const float* Wv    = (const float*)d_in[5];
  const float* bv    = (const float*)d_in[6];
  const float* gamma = (const float*)d_in[7];
  float* out = (float*)d_out;

  char* w = (char*)d_ws;
  u16* X3 = (u16*)(w);                         // 512*40*32*8 (10485760 B)
  u16* W3 = (u16*)(w + 10485760);              // 14*40*32*8  (286720 B)
  u16* Qb = (u16*)(w + 10772480);              // Q3: 8*64*8*32*8 (2097152 B)
  u16* Kb = (u16*)(w + 12869632);              // 16384*64    (2097152 B)
  u16* Vt = (u16*)(w + 14966784);              // V3: 8*256*320*8 (10485760 B)

  cvt_x_blk<<<512, 256, 0, stream>>>(x, X3);
  cvt_w_blk<<<14, 256, 0, stream>>>(Wq, Wk, Wv, W3);
  gemm_qkv<<<896, 256, 0, stream>>>(X3, W3, bq, bk, bv, Qb, Kb, Vt);
  row_stats<<<256, 512, 0, stream>>>(Qb, Kb, Vt);
  attn<<<512, 256, 0, stream>>>(Qb, Kb, Vt, x, gamma, out);
}

// Round 15
// 83.040 us; speedup vs baseline: 1.4195x; 1.0490x over previous
//
#include <hip/hip_runtime.h>
#include <hip/hip_bf16.h>

#define BB 8
#define NN 2048
#define CC 320
#define CQ 64
#define LOG2E 1.4426950408889634f

typedef __attribute__((ext_vector_type(8)))  short bf16x8;
typedef __attribute__((ext_vector_type(4)))  float f32x4;
typedef __attribute__((ext_vector_type(16))) float f32x16;
typedef __attribute__((ext_vector_type(4)))  unsigned short us4;
typedef __attribute__((ext_vector_type(8)))  unsigned short us8;
typedef __attribute__((ext_vector_type(4)))  unsigned int u32x4;
typedef unsigned short u16;

// Layouts:
//  X3[mt=m/32][kk8=k/8][ml=m%32][8]       (bf16; lane-contiguous A-frags)
//  W3[ct=c/32][kk8=k/8][cl=c%32][8]       (bf16; lane-contiguous B-frags)
//  Q3[b][kt=k/32][cq8=cq/8][kl=k%32][8]   (bf16, pre-scaled by log2e)
//  Kb[b*N+n][cq]                          (row-major)
//  V3[b][kt8=k/8][c][8]                   (bf16, UNSCALED — read-only)
//  Lb[b*N+k]                              (f32, log2 of softmax row sum)

static __device__ __forceinline__ u16 f2b(float f) {
  unsigned u = __builtin_bit_cast(unsigned, f);
  unsigned r = (u + 0x7FFFu + ((u >> 16) & 1u)) >> 16;
  return (u16)r;
}
static __device__ __forceinline__ float b2f(u16 s) {
  unsigned u = ((unsigned)s) << 16;
  return __builtin_bit_cast(float, u);
}

static __device__ __forceinline__ f32x16 zero16() {
  f32x16 v = {0,0,0,0, 0,0,0,0, 0,0,0,0, 0,0,0,0};
  return v;
}
static __device__ __forceinline__ f32x4 zero4() {
  f32x4 v = {0,0,0,0};
  return v;
}

static __device__ __forceinline__ void gll16(const void* g, void* l) {
  __builtin_amdgcn_global_load_lds(
      (const __attribute__((address_space(1))) unsigned int*)g,
      (__attribute__((address_space(3))) unsigned int*)l, 16, 0, 0);
}

// 8 fp32 -> bf16x8 via hardware packed converts (RNE, same as f2b)
static __device__ __forceinline__ bf16x8 cvt8(float4 a, float4 b) {
  unsigned p0, p1, p2, p3;
  asm("v_cvt_pk_bf16_f32 %0, %1, %2" : "=v"(p0) : "v"(a.x), "v"(a.y));
  asm("v_cvt_pk_bf16_f32 %0, %1, %2" : "=v"(p1) : "v"(a.z), "v"(a.w));
  asm("v_cvt_pk_bf16_f32 %0, %1, %2" : "=v"(p2) : "v"(b.x), "v"(b.y));
  asm("v_cvt_pk_bf16_f32 %0, %1, %2" : "=v"(p3) : "v"(b.z), "v"(b.w));
  u32x4 w = {p0, p1, p2, p3};
  return __builtin_bit_cast(bf16x8, w);
}

// ---------------------------------------------------------------------------
// K0: fused conversion. blocks 0..511: x -> X3; blocks 512..525: W -> W3.
// grid 526 x 256.
// ---------------------------------------------------------------------------
__global__ __launch_bounds__(256) void cvt_blk(const float* __restrict__ x,
                                               const float* __restrict__ Wq,
                                               const float* __restrict__ Wk,
                                               const float* __restrict__ Wv,
                                               u16* __restrict__ X3,
                                               u16* __restrict__ W3) {
  __shared__ float xs[32][324];   // +4 pad: conflict-free transpose reads
  const int t = threadIdx.x;
  const int bid = blockIdx.x;
  const bool isX = (bid < 512);
  const int b = isX ? bid : (bid - 512);
#pragma unroll
  for (int i = 0; i < 10; ++i) {
    const int lidx = i * 256 + t;        // 0..2559 float4 units
    const int m = lidx / 80;             // 80 float4 per row
    const int kq = lidx - m * 80;
    const float* src;
    if (isX) {
      src = x + (size_t)(b * 32 + m) * CC;
    } else {
      const int row = b * 32 + m;
      src = (row < 64) ? (Wq + (size_t)row * CC)
          : (row < 128) ? (Wk + (size_t)(row - 64) * CC)
                        : (Wv + (size_t)(row - 128) * CC);
    }
    float4 v = *(const float4*)(src + kq * 4);
    *(float4*)&xs[m][kq * 4] = v;
  }
  __syncthreads();
  u16* dst0 = (isX ? X3 : W3) + (size_t)b * 10240;
#pragma unroll
  for (int i = 0; i < 5; ++i) {
    const int u = i * 256 + t;           // 0..1279: kk8*32 + ml
    const int kk8 = u >> 5, ml = u & 31;
    float4 a = *(const float4*)&xs[ml][kk8 * 8];
    float4 c = *(const float4*)&xs[ml][kk8 * 8 + 4];
    bf16x8 o = cvt8(a, c);
    *(bf16x8*)(dst0 + (size_t)u * 8) = o;
  }
}

// ---------------------------------------------------------------------------
// K1: QKV GEMM from blocked X3/W3 (8-line requests), XCD-aware remap.
// grid 896 x 256.
// ---------------------------------------------------------------------------
__global__ __launch_bounds__(256) void gemm_qkv(
    const u16* __restrict__ X3, const u16* __restrict__ W3,
    const float* __restrict__ bq, const float* __restrict__ bk,
    const float* __restrict__ bv,
    u16* __restrict__ Qb, u16* __restrict__ Kb, u16* __restrict__ Vt) {
  const int tid = threadIdx.x;
  const int lane = tid & 63, wid = tid >> 6;
  const int r = lane & 31, h = lane >> 5;
  const int bid = blockIdx.x;
  const int xcd = bid & 7;
  const int slot = bid >> 3;          // 0..111
  const int colt = slot % 7;          // 0..6
  const int yG = slot / 7;            // 0..15
  const int ytile = yG * 8 + xcd;     // 0..127
  const int m0 = ytile * 128 + wid * 32;
  const int col0 = colt * 64;
  const int mt = m0 >> 5;

  const u16* abase  = X3 + (size_t)mt * 10240 + (size_t)h * 256 + r * 8;
  const u16* b0base = W3 + (size_t)(colt * 2) * 10240 + (size_t)h * 256 + r * 8;
  const u16* b1base = b0base + 10240;

  f32x16 acc0 = zero16(), acc1 = zero16();
  bf16x8 a   = *(const bf16x8*)(abase);
  bf16x8 b0v = *(const bf16x8*)(b0base);
  bf16x8 b1v = *(const bf16x8*)(b1base);
#pragma unroll 1
  for (int ks = 0; ks < 20; ++ks) {
    bf16x8 na, nb0, nb1;
    if (ks < 19) {
      na  = *(const bf16x8*)(abase  + (ks + 1) * 512);
      nb0 = *(const bf16x8*)(b0base + (ks + 1) * 512);
      nb1 = *(const bf16x8*)(b1base + (ks + 1) * 512);
    }
    acc0 = __builtin_amdgcn_mfma_f32_32x32x16_bf16(a, b0v, acc0, 0, 0, 0);
    acc1 = __builtin_amdgcn_mfma_f32_32x32x16_bf16(a, b1v, acc1, 0, 0, 0);
    a = na; b0v = nb0; b1v = nb1;
  }

  const int bb = m0 >> 11;        // batch
  const int mloc = m0 & 2047;     // n (or k) within batch

#pragma unroll
  for (int nt = 0; nt < 2; ++nt) {
    const int col = col0 + nt * 32 + r;
    const f32x16 A = nt ? acc1 : acc0;
    if (col0 >= 128) {
      const int c = col - 128;
      const float bias = bv[c];
      u16* vdst = Vt + (((size_t)(bb * 256 + (mloc >> 3)) * 320 + c) * 8) + 4 * h;
#pragma unroll
      for (int g = 0; g < 4; ++g) {
        us4 o;
#pragma unroll
        for (int e = 0; e < 4; ++e) o[e] = f2b(A[g * 4 + e] + bias);
        *(us4*)(vdst + (size_t)g * 2560) = o;
      }
    } else if (col0 >= 64) {
      const float bias = bk[col - 64];
#pragma unroll
      for (int reg = 0; reg < 16; ++reg) {
        const int row = m0 + (reg & 3) + 8 * (reg >> 2) + 4 * h;
        Kb[(size_t)row * CQ + (col - 64)] = f2b(A[reg] + bias);
      }
    } else {
      const float bias = bq[col];
      const int kt = mloc >> 5;
      u16* qdst = Qb + (((size_t)(bb * 64 + kt) * 8 + (col >> 3)) * 32) * 8 + (col & 7);
#pragma unroll
      for (int reg = 0; reg < 16; ++reg) {
        const int kl = (reg & 3) + 8 * (reg >> 2) + 4 * h;
        qdst[kl * 8] = f2b((A[reg] + bias) * LOG2E);
      }
    }
  }
}

// ---------------------------------------------------------------------------
// K3: row sums -> Lb[k] = log2(S[k]). 8 waves (512 thr), grid 256.
// (V-scale pass removed: normalization now happens in attn's exponent.)
// ---------------------------------------------------------------------------
__global__ __launch_bounds__(512) void row_stats(
    const u16* __restrict__ Qb, const u16* __restrict__ Kb,
    float* __restrict__ Lb) {
  __shared__ float Sp[8][64];
  const int tid = threadIdx.x;
  const int lane = tid & 63, wid = tid >> 6;   // 0..7
  const int rl = lane & 15, hq = lane >> 4;
  const int bid = blockIdx.x;
  const int batch = bid & 7;
  const int kloc64 = (bid >> 3) * 64;          // bid>>3 in [0,32)

  bf16x8 af[4][2];
#pragma unroll
  for (int mt = 0; mt < 4; ++mt) {
    const int k_loc = kloc64 + mt * 16 + rl;
    const int kt = k_loc >> 5, kl = k_loc & 31;
#pragma unroll
    for (int qs = 0; qs < 2; ++qs)
      af[mt][qs] = *(const bf16x8*)(Qb +
          (((size_t)(batch * 64 + kt) * 8 + qs * 4 + hq) * 32 + kl) * 8);
  }

  float S[4][4];
#pragma unroll
  for (int mt = 0; mt < 4; ++mt)
#pragma unroll
    for (int rr = 0; rr < 4; ++rr) S[mt][rr] = 0.f;

  const int mstart = batch * NN + wid * 256;
  const u16* kr = Kb + (size_t)(mstart + rl) * CQ + hq * 8;
  bf16x8 c0 = *(const bf16x8*)(kr);
  bf16x8 c1 = *(const bf16x8*)(kr + 32);
#pragma unroll 1
  for (int ms = 0; ms < 16; ++ms) {
    bf16x8 n0, n1;
    if (ms < 15) {
      n0 = *(const bf16x8*)(kr + 16 * CQ);
      n1 = *(const bf16x8*)(kr + 16 * CQ + 32);
    }
#pragma unroll
    for (int mt = 0; mt < 4; ++mt) {
      f32x4 e = zero4();
      e = __builtin_amdgcn_mfma_f32_16x16x32_bf16(af[mt][0], c0, e, 0, 0, 0);
      e = __builtin_amdgcn_mfma_f32_16x16x32_bf16(af[mt][1], c1, e, 0, 0, 0);
#pragma unroll
      for (int rr = 0; rr < 4; ++rr) S[mt][rr] += __builtin_amdgcn_exp2f(e[rr]);
    }
    c0 = n0; c1 = n1; kr += 16 * CQ;
  }

#pragma unroll
  for (int d = 1; d < 16; d <<= 1)
#pragma unroll
    for (int mt = 0; mt < 4; ++mt)
#pragma unroll
      for (int rr = 0; rr < 4; ++rr) S[mt][rr] += __shfl_xor(S[mt][rr], d, 64);

  if (rl == 0) {
#pragma unroll
    for (int mt = 0; mt < 4; ++mt)
#pragma unroll
      for (int rr = 0; rr < 4; ++rr) Sp[wid][mt * 16 + hq * 4 + rr] = S[mt][rr];
  }
  __syncthreads();
  if (tid < 64) {
    float s = 0.f;
#pragma unroll
    for (int p = 0; p < 8; ++p) s += Sp[p][tid];
    Lb[batch * NN + kloc64 + tid] = __log2f(s);
  }
}

// ---------------------------------------------------------------------------
// K4: attention v10 — V-only LDS staging, Q + L(=log2 S) register-prefetched
// one tile ahead (named A/B). P = 2^(E' - L[k]) normalizes in the exponent.
// Same barrier skeleton as passing v7/v9: STAGE(t+1) -> COMPUTE(t) -> bar.
// Block = 256 thr = 4 waves: (wn n-tile 0/1) x (kh k-half 0/1).
// Grid 512 = 8b x 2ch x 32 n-pairs; batch = bid&7 (XCD-pinned).
// ---------------------------------------------------------------------------
__global__ __launch_bounds__(256, 2) void attn(
    const u16* __restrict__ Qb, const u16* __restrict__ Kb,
    const u16* __restrict__ Vt, const float* __restrict__ Lb,
    const float* __restrict__ x, const float* __restrict__ gamma,
    float* __restrict__ out) {
  __shared__ __align__(16) char LDSRAW[40960];   // 2 bufs x 2 kh x 10240 (V)
  const int tid = threadIdx.x;
  const int lane = tid & 63, wid = tid >> 6;
  const int wn = wid >> 1;       // n-tile within pair
  const int kh = wid & 1;        // k-half
  const int r = lane & 31, h = lane >> 5;
  const int bid = blockIdx.x;
  const int b = bid & 7;
  const int rest = bid >> 3;
  const int ch = rest & 1;
  const int n0 = (rest >> 1) * 64;

  // K fragments for n-tile n0 + wn*32 (held all k)
  bf16x8 kf[4];
  {
    const u16* krow = Kb + (size_t)(b * NN + n0 + wn * 32 + r) * CQ + h * 8;
#pragma unroll
    for (int qs = 0; qs < 4; ++qs) kf[qs] = *(const bf16x8*)(krow + qs * 16);
  }

  f32x16 acc[5];
#pragma unroll
  for (int j = 0; j < 5; ++j) acc[j] = zero16();

  // per-wave bases for this k-half
  const u16* qb3 = Qb + ((size_t)(b * 64 + kh * 32) * 8) * 256 + (size_t)r * 8;
  const float* lbase = Lb + b * NN + kh * 1024 + 4 * h;

  // stage V only: 20 chunks of 1KB (10 per kh), wave w takes [w*5, w*5+5)
#define STAGE(TN, BUF) {                                                       \
    _Pragma("unroll")                                                          \
    for (int i_ = 0; i_ < 5; ++i_) {                                           \
      const int c_ = wid * 5 + i_;                                             \
      const int khc_ = c_ / 10;                                                \
      const int rem_ = c_ % 10;                                                \
      char* dst_ = LDSRAW + (BUF) * 20480 + khc_ * 10240 + rem_ * 1024;        \
      const int off_ = rem_ * 512 + lane * 8;                                  \
      const int row_ = off_ / 1280;                                            \
      const int win_ = off_ - row_ * 1280;                                     \
      const u16* src_ = Vt +                                                   \
          ((size_t)(b * 256 + khc_ * 128 + (TN) * 4 + row_) * 320              \
           + ch * 160) * 8 + win_;                                             \
      gll16(src_, dst_);                                                       \
    }                                                                          \
  }

// prefetch Q frags + L quads for tile TN into QN / LN
#define LQ(QN, LN, TN) {                                                       \
    _Pragma("unroll")                                                          \
    for (int qs = 0; qs < 4; ++qs)                                             \
      QN[qs] = *(const bf16x8*)(qb3 + ((size_t)(TN) * 8 + qs * 2 + h) * 256);  \
    _Pragma("unroll")                                                          \
    for (int g = 0; g < 4; ++g)                                                \
      LN[g] = *(const float4*)(lbase + (TN) * 32 + g * 8);                     \
  }

// compute tile T from LDS buffer BUF using prefetched QF/LF; prefetch for TNX
#define COMPUTE(T, BUF, QF, LF, QN, LN, TNX) {                                 \
    LQ(QN, LN, TNX)                                                            \
    const char* base_ = LDSRAW + (BUF) * 20480 + kh * 10240;                   \
    f32x16 e = zero16();                                                       \
    _Pragma("unroll")                                                          \
    for (int qs = 0; qs < 4; ++qs)                                             \
      e = __builtin_amdgcn_mfma_f32_32x32x16_bf16(QF[qs], kf[qs], e, 0, 0, 0); \
    bf16x8 vf[5][2];                                                           \
    _Pragma("unroll")                                                          \
    for (int j = 0; j < 5; ++j)                                                \
      _Pragma("unroll")                                                        \
      for (int ks = 0; ks < 2; ++ks)                                           \
        vf[j][ks] = *(const bf16x8*)(base_ + (ks * 2 + h) * 2560               \
                                     + (j * 32 + r) * 16);                     \
    unsigned pk0, pk1, pk2, pk3, pk4, pk5, pk6, pk7;                           \
    { float l0 = __builtin_amdgcn_exp2f(e[0]  - LF[0].x);                      \
      float h0 = __builtin_amdgcn_exp2f(e[1]  - LF[0].y);                      \
      float l1 = __builtin_amdgcn_exp2f(e[2]  - LF[0].z);                      \
      float h1 = __builtin_amdgcn_exp2f(e[3]  - LF[0].w);                      \
      float l2 = __builtin_amdgcn_exp2f(e[4]  - LF[1].x);                      \
      float h2 = __builtin_amdgcn_exp2f(e[5]  - LF[1].y);                      \
      float l3 = __builtin_amdgcn_exp2f(e[6]  - LF[1].z);                      \
      float h3 = __builtin_amdgcn_exp2f(e[7]  - LF[1].w);                      \
      float l4 = __builtin_amdgcn_exp2f(e[8]  - LF[2].x);                      \
      float h4 = __builtin_amdgcn_exp2f(e[9]  - LF[2].y);                      \
      float l5 = __builtin_amdgcn_exp2f(e[10] - LF[2].z);                      \
      float h5 = __builtin_amdgcn_exp2f(e[11] - LF[2].w);                      \
      float l6 = __builtin_amdgcn_exp2f(e[12] - LF[3].x);                      \
      float h6 = __builtin_amdgcn_exp2f(e[13] - LF[3].y);                      \
      float l7 = __builtin_amdgcn_exp2f(e[14] - LF[3].z);                      \
      float h7 = __builtin_amdgcn_exp2f(e[15] - LF[3].w);                      \
      asm("v_cvt_pk_bf16_f32 %0, %1, %2" : "=v"(pk0) : "v"(l0), "v"(h0));      \
      asm("v_cvt_pk_bf16_f32 %0, %1, %2" : "=v"(pk1) : "v"(l1), "v"(h1));      \
      asm("v_cvt_pk_bf16_f32 %0, %1, %2" : "=v"(pk2) : "v"(l2), "v"(h2));      \
      asm("v_cvt_pk_bf16_f32 %0, %1, %2" : "=v"(pk3) : "v"(l3), "v"(h3));      \
      asm("v_cvt_pk_bf16_f32 %0, %1, %2" : "=v"(pk4) : "v"(l4), "v"(h4));      \
      asm("v_cvt_pk_bf16_f32 %0, %1, %2" : "=v"(pk5) : "v"(l5), "v"(h5));      \
      asm("v_cvt_pk_bf16_f32 %0, %1, %2" : "=v"(pk6) : "v"(l6), "v"(h6));      \
      asm("v_cvt_pk_bf16_f32 %0, %1, %2" : "=v"(pk7) : "v"(l7), "v"(h7)); }    \
    asm("v_permlane32_swap_b32 %0, %1" : "+v"(pk0), "+v"(pk2));                \
    asm("v_permlane32_swap_b32 %0, %1" : "+v"(pk1), "+v"(pk3));                \
    asm("v_permlane32_swap_b32 %0, %1" : "+v"(pk4), "+v"(pk6));                \
    asm("v_permlane32_swap_b32 %0, %1" : "+v"(pk5), "+v"(pk7));                \
    u32x4 w0_ = {pk0, pk1, pk2, pk3};                                          \
    u32x4 w1_ = {pk4, pk5, pk6, pk7};                                          \
    bf16x8 pa0 = __builtin_bit_cast(bf16x8, w0_);                              \
    bf16x8 pa1 = __builtin_bit_cast(bf16x8, w1_);                              \
    _Pragma("unroll")                                                          \
    for (int j = 0; j < 5; ++j) {                                              \
      acc[j] = __builtin_amdgcn_mfma_f32_32x32x16_bf16(pa0, vf[j][0], acc[j], 0, 0, 0); \
      acc[j] = __builtin_amdgcn_mfma_f32_32x32x16_bf16(pa1, vf[j][1], acc[j], 0, 0, 0); \
    }                                                                          \
  }

  bf16x8 qfA[4], qfB[4];
  float4 lfA[4], lfB[4];

  STAGE(0, 0);
  LQ(qfA, lfA, 0)
  __syncthreads();
#pragma unroll 1
  for (int t = 0; t < 32; t += 2) {
    STAGE(t + 1, 1);                               // odd tile -> buf1
    COMPUTE(t, 0, qfA, lfA, qfB, lfB, t + 1);      // even tile from buf0
    __syncthreads();
    if (t + 2 < 32) STAGE(t + 2, 0);               // even tile -> buf0
    COMPUTE(t + 1, 1, qfB, lfB, qfA, lfA, (t + 2) & 31); // odd tile from buf1
    __syncthreads();
  }
#undef STAGE
#undef LQ
#undef COMPUTE

  // kh=1 waves dump partial sums; kh=0 waves combine and write out
  float* red = (float*)LDSRAW;   // 2 regions x 5120 f32 = 40960 B (fits)
  if (kh == 1) {
#pragma unroll
    for (int reg = 0; reg < 16; ++reg) {
      const int nl = (reg & 3) + 8 * (reg >> 2) + 4 * h;
#pragma unroll
      for (int j = 0; j < 5; ++j)
        red[wn * 5120 + nl * 160 + j * 32 + r] = acc[j][reg];
    }
  }
  __syncthreads();
  if (kh == 0) {
    const float g = gamma[0];
#pragma unroll
    for (int reg = 0; reg < 16; ++reg) {
      const int nl = (reg & 3) + 8 * (reg >> 2) + 4 * h;
      const size_t rowb = ((size_t)(b * NN) + n0 + wn * 32 + nl) * CC + ch * 160 + r;
#pragma unroll
      for (int j = 0; j < 5; ++j) {
        const size_t idx = rowb + (size_t)(j * 32);
        const float s = acc[j][reg] + red[wn * 5120 + nl * 160 + j * 32 + r];
        out[idx] = g * s + x[idx];
      }
    }
  }
}

extern "C" void kernel_launch(void* const* d_in, const int* in_sizes, int n_in,
                              void* d_out, int out_size, void* d_ws, size_t ws_size,
                              hipStream_t stream) {
  const float* x     = (const float*)d_in[0];
  const float* Wq    = (const float*)d_in[1];
  const float* bq    = (const float*)d_in[2];
  const float* Wk    = (const float*)d_in[3];
  const float* bk    = (const float*)d_in[4];
  const float* Wv    = (const float*)d_in[5];
  const float* bv    = (const float*)d_in[6];
  const float* gamma = (const float*)d_in[7];
  float* out = (float*)d_out;

  char* w = (char*)d_ws;
  u16* X3   = (u16*)(w);                       // 512*40*32*8 (10485760 B)
  u16* W3   = (u16*)(w + 10485760);            // 14*40*32*8  (286720 B)
  u16* Qb   = (u16*)(w + 10772480);            // Q3: 8*64*8*32*8 (2097152 B)
  u16* Kb   = (u16*)(w + 12869632);            // 16384*64    (2097152 B)
  u16* Vt   = (u16*)(w + 14966784);            // V3: 8*256*320*8 (10485760 B)
  float* Lb = (float*)(w + 25452544);          // 16384 f32   (65536 B)

  cvt_blk<<<526, 256, 0, stream>>>(x, Wq, Wk, Wv, X3, W3);
  gemm_qkv<<<896, 256, 0, stream>>>(X3, W3, bq, bk, bv, Qb, Kb, Vt);
  row_stats<<<256, 512, 0, stream>>>(Qb, Kb, Lb);
  attn<<<512, 256, 0, stream>>>(Qb, Kb, Vt, Lb, x, gamma, out);
}

// Round 17
// 82.085 us; speedup vs baseline: 1.4360x; 1.0116x over previous
//
#include <hip/hip_runtime.h>
#include <hip/hip_bf16.h>

#define BB 8
#define NN 2048
#define CC 320
#define CQ 64
#define LOG2E 1.4426950408889634f

typedef __attribute__((ext_vector_type(8)))  short bf16x8;
typedef __attribute__((ext_vector_type(4)))  float f32x4;
typedef __attribute__((ext_vector_type(16))) float f32x16;
typedef __attribute__((ext_vector_type(4)))  unsigned short us4;
typedef __attribute__((ext_vector_type(8)))  unsigned short us8;
typedef __attribute__((ext_vector_type(4)))  unsigned int u32x4;
typedef unsigned short u16;

// Layouts:
//  X3[mt=m/32][kk8=k/8][ml=m%32][8]       (bf16; lane-contiguous A-frags)
//  W3[ct=c/32][kk8=k/8][cl=c%32][8]       (bf16; lane-contiguous B-frags)
//  Q3[b][kt=k/32][cq8=cq/8][kl=k%32][8]   (bf16, pre-scaled by log2e)
//  Kb[b*N+n][cq]                          (row-major)
//  V3[b][kt8=k/8][c][8]                   (bf16, UNSCALED — read-only)
//  Lb[b*N+k]                              (f32, log2 of softmax row sum)

static __device__ __forceinline__ u16 f2b(float f) {
  unsigned u = __builtin_bit_cast(unsigned, f);
  unsigned r = (u + 0x7FFFu + ((u >> 16) & 1u)) >> 16;
  return (u16)r;
}
static __device__ __forceinline__ float b2f(u16 s) {
  unsigned u = ((unsigned)s) << 16;
  return __builtin_bit_cast(float, u);
}

static __device__ __forceinline__ f32x16 zero16() {
  f32x16 v = {0,0,0,0, 0,0,0,0, 0,0,0,0, 0,0,0,0};
  return v;
}
static __device__ __forceinline__ f32x4 zero4() {
  f32x4 v = {0,0,0,0};
  return v;
}

static __device__ __forceinline__ void gll16(const void* g, void* l) {
  __builtin_amdgcn_global_load_lds(
      (const __attribute__((address_space(1))) unsigned int*)g,
      (__attribute__((address_space(3))) unsigned int*)l, 16, 0, 0);
}

// 8 fp32 -> bf16x8 via hardware packed converts (RNE, same as f2b)
static __device__ __forceinline__ bf16x8 cvt8(float4 a, float4 b) {
  unsigned p0, p1, p2, p3;
  asm("v_cvt_pk_bf16_f32 %0, %1, %2" : "=v"(p0) : "v"(a.x), "v"(a.y));
  asm("v_cvt_pk_bf16_f32 %0, %1, %2" : "=v"(p1) : "v"(a.z), "v"(a.w));
  asm("v_cvt_pk_bf16_f32 %0, %1, %2" : "=v"(p2) : "v"(b.x), "v"(b.y));
  asm("v_cvt_pk_bf16_f32 %0, %1, %2" : "=v"(p3) : "v"(b.z), "v"(b.w));
  u32x4 w = {p0, p1, p2, p3};
  return __builtin_bit_cast(bf16x8, w);
}

// ---------------------------------------------------------------------------
// K0: fused conversion. blocks 0..511: x -> X3; blocks 512..525: W -> W3.
// grid 526 x 256.
// ---------------------------------------------------------------------------
__global__ __launch_bounds__(256) void cvt_blk(const float* __restrict__ x,
                                               const float* __restrict__ Wq,
                                               const float* __restrict__ Wk,
                                               const float* __restrict__ Wv,
                                               u16* __restrict__ X3,
                                               u16* __restrict__ W3) {
  __shared__ float xs[32][324];   // +4 pad: conflict-free transpose reads
  const int t = threadIdx.x;
  const int bid = blockIdx.x;
  const bool isX = (bid < 512);
  const int b = isX ? bid : (bid - 512);
#pragma unroll
  for (int i = 0; i < 10; ++i) {
    const int lidx = i * 256 + t;        // 0..2559 float4 units
    const int m = lidx / 80;             // 80 float4 per row
    const int kq = lidx - m * 80;
    const float* src;
    if (isX) {
      src = x + (size_t)(b * 32 + m) * CC;
    } else {
      const int row = b * 32 + m;
      src = (row < 64) ? (Wq + (size_t)row * CC)
          : (row < 128) ? (Wk + (size_t)(row - 64) * CC)
                        : (Wv + (size_t)(row - 128) * CC);
    }
    float4 v = *(const float4*)(src + kq * 4);
    *(float4*)&xs[m][kq * 4] = v;
  }
  __syncthreads();
  u16* dst0 = (isX ? X3 : W3) + (size_t)b * 10240;
#pragma unroll
  for (int i = 0; i < 5; ++i) {
    const int u = i * 256 + t;           // 0..1279: kk8*32 + ml
    const int kk8 = u >> 5, ml = u & 31;
    float4 a = *(const float4*)&xs[ml][kk8 * 8];
    float4 c = *(const float4*)&xs[ml][kk8 * 8 + 4];
    bf16x8 o = cvt8(a, c);
    *(bf16x8*)(dst0 + (size_t)u * 8) = o;
  }
}

// ---------------------------------------------------------------------------
// K1: QKV GEMM from blocked X3/W3 (8-line requests), XCD-aware remap.
// grid 896 x 256.
// ---------------------------------------------------------------------------
__global__ __launch_bounds__(256) void gemm_qkv(
    const u16* __restrict__ X3, const u16* __restrict__ W3,
    const float* __restrict__ bq, const float* __restrict__ bk,
    const float* __restrict__ bv,
    u16* __restrict__ Qb, u16* __restrict__ Kb, u16* __restrict__ Vt) {
  const int tid = threadIdx.x;
  const int lane = tid & 63, wid = tid >> 6;
  const int r = lane & 31, h = lane >> 5;
  const int bid = blockIdx.x;
  const int xcd = bid & 7;
  const int slot = bid >> 3;          // 0..111
  const int colt = slot % 7;          // 0..6
  const int yG = slot / 7;            // 0..15
  const int ytile = yG * 8 + xcd;     // 0..127
  const int m0 = ytile * 128 + wid * 32;
  const int col0 = colt * 64;
  const int mt = m0 >> 5;

  const u16* abase  = X3 + (size_t)mt * 10240 + (size_t)h * 256 + r * 8;
  const u16* b0base = W3 + (size_t)(colt * 2) * 10240 + (size_t)h * 256 + r * 8;
  const u16* b1base = b0base + 10240;

  f32x16 acc0 = zero16(), acc1 = zero16();
  bf16x8 a   = *(const bf16x8*)(abase);
  bf16x8 b0v = *(const bf16x8*)(b0base);
  bf16x8 b1v = *(const bf16x8*)(b1base);
#pragma unroll 1
  for (int ks = 0; ks < 20; ++ks) {
    bf16x8 na, nb0, nb1;
    if (ks < 19) {
      na  = *(const bf16x8*)(abase  + (ks + 1) * 512);
      nb0 = *(const bf16x8*)(b0base + (ks + 1) * 512);
      nb1 = *(const bf16x8*)(b1base + (ks + 1) * 512);
    }
    acc0 = __builtin_amdgcn_mfma_f32_32x32x16_bf16(a, b0v, acc0, 0, 0, 0);
    acc1 = __builtin_amdgcn_mfma_f32_32x32x16_bf16(a, b1v, acc1, 0, 0, 0);
    a = na; b0v = nb0; b1v = nb1;
  }

  const int bb = m0 >> 11;        // batch
  const int mloc = m0 & 2047;     // n (or k) within batch

#pragma unroll
  for (int nt = 0; nt < 2; ++nt) {
    const int col = col0 + nt * 32 + r;
    const f32x16 A = nt ? acc1 : acc0;
    if (col0 >= 128) {
      const int c = col - 128;
      const float bias = bv[c];
      u16* vdst = Vt + (((size_t)(bb * 256 + (mloc >> 3)) * 320 + c) * 8) + 4 * h;
#pragma unroll
      for (int g = 0; g < 4; ++g) {
        us4 o;
#pragma unroll
        for (int e = 0; e < 4; ++e) o[e] = f2b(A[g * 4 + e] + bias);
        *(us4*)(vdst + (size_t)g * 2560) = o;
      }
    } else if (col0 >= 64) {
      const float bias = bk[col - 64];
#pragma unroll
      for (int reg = 0; reg < 16; ++reg) {
        const int row = m0 + (reg & 3) + 8 * (reg >> 2) + 4 * h;
        Kb[(size_t)row * CQ + (col - 64)] = f2b(A[reg] + bias);
      }
    } else {
      const float bias = bq[col];
      const int kt = mloc >> 5;
      u16* qdst = Qb + (((size_t)(bb * 64 + kt) * 8 + (col >> 3)) * 32) * 8 + (col & 7);
#pragma unroll
      for (int reg = 0; reg < 16; ++reg) {
        const int kl = (reg & 3) + 8 * (reg >> 2) + 4 * h;
        qdst[kl * 8] = f2b((A[reg] + bias) * LOG2E);
      }
    }
  }
}

// ---------------------------------------------------------------------------
// K3: row sums -> Lb[k] = log2(S[k]). 8 waves (512 thr), grid 256.
// ---------------------------------------------------------------------------
__global__ __launch_bounds__(512) void row_stats(
    const u16* __restrict__ Qb, const u16* __restrict__ Kb,
    float* __restrict__ Lb) {
  __shared__ float Sp[8][64];
  const int tid = threadIdx.x;
  const int lane = tid & 63, wid = tid >> 6;   // 0..7
  const int rl = lane & 15, hq = lane >> 4;
  const int bid = blockIdx.x;
  const int batch = bid & 7;
  const int kloc64 = (bid >> 3) * 64;          // bid>>3 in [0,32)

  bf16x8 af[4][2];
#pragma unroll
  for (int mt = 0; mt < 4; ++mt) {
    const int k_loc = kloc64 + mt * 16 + rl;
    const int kt = k_loc >> 5, kl = k_loc & 31;
#pragma unroll
    for (int qs = 0; qs < 2; ++qs)
      af[mt][qs] = *(const bf16x8*)(Qb +
          (((size_t)(batch * 64 + kt) * 8 + qs * 4 + hq) * 32 + kl) * 8);
  }

  float S[4][4];
#pragma unroll
  for (int mt = 0; mt < 4; ++mt)
#pragma unroll
    for (int rr = 0; rr < 4; ++rr) S[mt][rr] = 0.f;

  const int mstart = batch * NN + wid * 256;
  const u16* kr = Kb + (size_t)(mstart + rl) * CQ + hq * 8;
  bf16x8 c0 = *(const bf16x8*)(kr);
  bf16x8 c1 = *(const bf16x8*)(kr + 32);
#pragma unroll 1
  for (int ms = 0; ms < 16; ++ms) {
    bf16x8 n0, n1;
    if (ms < 15) {
      n0 = *(const bf16x8*)(kr + 16 * CQ);
      n1 = *(const bf16x8*)(kr + 16 * CQ + 32);
    }
#pragma unroll
    for (int mt = 0; mt < 4; ++mt) {
      f32x4 e = zero4();
      e = __builtin_amdgcn_mfma_f32_16x16x32_bf16(af[mt][0], c0, e, 0, 0, 0);
      e = __builtin_amdgcn_mfma_f32_16x16x32_bf16(af[mt][1], c1, e, 0, 0, 0);
#pragma unroll
      for (int rr = 0; rr < 4; ++rr) S[mt][rr] += __builtin_amdgcn_exp2f(e[rr]);
    }
    c0 = n0; c1 = n1; kr += 16 * CQ;
  }

#pragma unroll
  for (int d = 1; d < 16; d <<= 1)
#pragma unroll
    for (int mt = 0; mt < 4; ++mt)
#pragma unroll
      for (int rr = 0; rr < 4; ++rr) S[mt][rr] += __shfl_xor(S[mt][rr], d, 64);

  if (rl == 0) {
#pragma unroll
    for (int mt = 0; mt < 4; ++mt)
#pragma unroll
      for (int rr = 0; rr < 4; ++rr) Sp[wid][mt * 16 + hq * 4 + rr] = S[mt][rr];
  }
  __syncthreads();
  if (tid < 64) {
    float s = 0.f;
#pragma unroll
    for (int p = 0; p < 8; ++p) s += Sp[p][tid];
    Lb[batch * NN + kloc64 + tid] = __log2f(s);
  }
}

// ---------------------------------------------------------------------------
// K4: attention v12 — r15-passing skeleton; L moved from per-tile VMEM loads
// to a ONE-TIME LDS stage (8 KB), read via ds_read (lgkm queue) so the exp
// chain never waits on the vmcnt queue behind global_load_lds stores.
// V-only LDS staging (40 KB, double-buffered), Q register-prefetched one
// tile ahead (named A/B). Skeleton: STAGE(t+1) -> COMPUTE(t) -> barrier.
// Block = 256 thr = 4 waves: (wn n-tile 0/1) x (kh k-half 0/1).
// Grid 512 = 8b x 2ch x 32 n-pairs; batch = bid&7 (XCD-pinned).
// ---------------------------------------------------------------------------
__global__ __launch_bounds__(256, 2) void attn(
    const u16* __restrict__ Qb, const u16* __restrict__ Kb,
    const u16* __restrict__ Vt, const float* __restrict__ Lb,
    const float* __restrict__ x, const float* __restrict__ gamma,
    float* __restrict__ out) {
  __shared__ __align__(16) char LDSRAW[49152];   // 40KB V bufs + 8KB L
  float* Ls = (float*)(LDSRAW + 40960);          // [2048] = both kh halves
  const int tid = threadIdx.x;
  const int lane = tid & 63, wid = tid >> 6;
  const int wn = wid >> 1;       // n-tile within pair
  const int kh = wid & 1;        // k-half
  const int r = lane & 31, h = lane >> 5;
  const int bid = blockIdx.x;
  const int b = bid & 7;
  const int rest = bid >> 3;
  const int ch = rest & 1;
  const int n0 = (rest >> 1) * 64;

  // one-time: stage this batch's L (2048 f32, 8 KB) into LDS
#pragma unroll
  for (int i = 0; i < 8; ++i)
    Ls[i * 256 + tid] = Lb[b * NN + i * 256 + tid];

  // K fragments for n-tile n0 + wn*32 (held all k)
  bf16x8 kf[4];
  {
    const u16* krow = Kb + (size_t)(b * NN + n0 + wn * 32 + r) * CQ + h * 8;
#pragma unroll
    for (int qs = 0; qs < 4; ++qs) kf[qs] = *(const bf16x8*)(krow + qs * 16);
  }

  f32x16 acc[5];
#pragma unroll
  for (int j = 0; j < 5; ++j) acc[j] = zero16();

  // per-wave bases for this k-half
  const u16* qb3 = Qb + ((size_t)(b * 64 + kh * 32) * 8) * 256 + (size_t)r * 8;
  const float* lsb = Ls + kh * 1024 + 4 * h;   // LDS pointer (per-lane via h)

  // stage V only: 20 chunks of 1KB (10 per kh), wave w takes [w*5, w*5+5)
#define STAGE(TN, BUF) {                                                       \
    _Pragma("unroll")                                                          \
    for (int i_ = 0; i_ < 5; ++i_) {                                           \
      const int c_ = wid * 5 + i_;                                             \
      const int khc_ = c_ / 10;                                                \
      const int rem_ = c_ % 10;                                                \
      char* dst_ = LDSRAW + (BUF) * 20480 + khc_ * 10240 + rem_ * 1024;        \
      const int off_ = rem_ * 512 + lane * 8;                                  \
      const int row_ = off_ / 1280;                                            \
      const int win_ = off_ - row_ * 1280;                                     \
      const u16* src_ = Vt +                                                   \
          ((size_t)(b * 256 + khc_ * 128 + (TN) * 4 + row_) * 320              \
           + ch * 160) * 8 + win_;                                             \
      gll16(src_, dst_);                                                       \
    }                                                                          \
  }

// prefetch Q frags for tile TN into QN (plain global loads, lane-contiguous)
#define LQ(QN, TN) {                                                           \
    _Pragma("unroll")                                                          \
    for (int qs = 0; qs < 4; ++qs)                                             \
      QN[qs] = *(const bf16x8*)(qb3 + ((size_t)(TN) * 8 + qs * 2 + h) * 256);  \
  }

// compute tile T from LDS buffer BUF using prefetched QF; prefetch QN (TNX);
// L read from LDS (broadcast ds_read_b128, lgkm queue)
#define COMPUTE(T, BUF, QF, QN, TNX) {                                         \
    LQ(QN, TNX)                                                                \
    float4 LF0 = *(const float4*)(lsb + (T) * 32);                             \
    float4 LF1 = *(const float4*)(lsb + (T) * 32 + 8);                         \
    float4 LF2 = *(const float4*)(lsb + (T) * 32 + 16);                        \
    float4 LF3 = *(const float4*)(lsb + (T) * 32 + 24);                        \
    const char* base_ = LDSRAW + (BUF) * 20480 + kh * 10240;                   \
    f32x16 e = zero16();                                                       \
    _Pragma("unroll")                                                          \
    for (int qs = 0; qs < 4; ++qs)                                             \
      e = __builtin_amdgcn_mfma_f32_32x32x16_bf16(QF[qs], kf[qs], e, 0, 0, 0); \
    bf16x8 vf[5][2];                                                           \
    _Pragma("unroll")                                                          \
    for (int j = 0; j < 5; ++j)                                                \
      _Pragma("unroll")                                                        \
      for (int ks = 0; ks < 2; ++ks)                                           \
        vf[j][ks] = *(const bf16x8*)(base_ + (ks * 2 + h) * 2560               \
                                     + (j * 32 + r) * 16);                     \
    unsigned pk0, pk1, pk2, pk3, pk4, pk5, pk6, pk7;                           \
    { float l0 = __builtin_amdgcn_exp2f(e[0]  - LF0.x);                        \
      float h0 = __builtin_amdgcn_exp2f(e[1]  - LF0.y);                        \
      float l1 = __builtin_amdgcn_exp2f(e[2]  - LF0.z);                        \
      float h1 = __builtin_amdgcn_exp2f(e[3]  - LF0.w);                        \
      float l2 = __builtin_amdgcn_exp2f(e[4]  - LF1.x);                        \
      float h2 = __builtin_amdgcn_exp2f(e[5]  - LF1.y);                        \
      float l3 = __builtin_amdgcn_exp2f(e[6]  - LF1.z);                        \
      float h3 = __builtin_amdgcn_exp2f(e[7]  - LF1.w);                        \
      float l4 = __builtin_amdgcn_exp2f(e[8]  - LF2.x);                        \
      float h4 = __builtin_amdgcn_exp2f(e[9]  - LF2.y);                        \
      float l5 = __builtin_amdgcn_exp2f(e[10] - LF2.z);                        \
      float h5 = __builtin_amdgcn_exp2f(e[11] - LF2.w);                        \
      float l6 = __builtin_amdgcn_exp2f(e[12] - LF3.x);                        \
      float h6 = __builtin_amdgcn_exp2f(e[13] - LF3.y);                        \
      float l7 = __builtin_amdgcn_exp2f(e[14] - LF3.z);                        \
      float h7 = __builtin_amdgcn_exp2f(e[15] - LF3.w);                        \
      asm("v_cvt_pk_bf16_f32 %0, %1, %2" : "=v"(pk0) : "v"(l0), "v"(h0));      \
      asm("v_cvt_pk_bf16_f32 %0, %1, %2" : "=v"(pk1) : "v"(l1), "v"(h1));      \
      asm("v_cvt_pk_bf16_f32 %0, %1, %2" : "=v"(pk2) : "v"(l2), "v"(h2));      \
      asm("v_cvt_pk_bf16_f32 %0, %1, %2" : "=v"(pk3) : "v"(l3), "v"(h3));      \
      asm("v_cvt_pk_bf16_f32 %0, %1, %2" : "=v"(pk4) : "v"(l4), "v"(h4));      \
      asm("v_cvt_pk_bf16_f32 %0, %1, %2" : "=v"(pk5) : "v"(l5), "v"(h5));      \
      asm("v_cvt_pk_bf16_f32 %0, %1, %2" : "=v"(pk6) : "v"(l6), "v"(h6));      \
      asm("v_cvt_pk_bf16_f32 %0, %1, %2" : "=v"(pk7) : "v"(l7), "v"(h7)); }    \
    asm("v_permlane32_swap_b32 %0, %1" : "+v"(pk0), "+v"(pk2));                \
    asm("v_permlane32_swap_b32 %0, %1" : "+v"(pk1), "+v"(pk3));                \
    asm("v_permlane32_swap_b32 %0, %1" : "+v"(pk4), "+v"(pk6));                \
    asm("v_permlane32_swap_b32 %0, %1" : "+v"(pk5), "+v"(pk7));                \
    u32x4 w0_ = {pk0, pk1, pk2, pk3};                                          \
    u32x4 w1_ = {pk4, pk5, pk6, pk7};                                          \
    bf16x8 pa0 = __builtin_bit_cast(bf16x8, w0_);                              \
    bf16x8 pa1 = __builtin_bit_cast(bf16x8, w1_);                              \
    _Pragma("unroll")                                                          \
    for (int j = 0; j < 5; ++j) {                                              \
      acc[j] = __builtin_amdgcn_mfma_f32_32x32x16_bf16(pa0, vf[j][0], acc[j], 0, 0, 0); \
      acc[j] = __builtin_amdgcn_mfma_f32_32x32x16_bf16(pa1, vf[j][1], acc[j], 0, 0, 0); \
    }                                                                          \
  }

  bf16x8 qfA[4], qfB[4];

  STAGE(0, 0);
  LQ(qfA, 0)
  __syncthreads();                 // V tile 0 staged + Ls filled (all waves)
#pragma unroll 1
  for (int t = 0; t < 32; t += 2) {
    STAGE(t + 1, 1);                          // odd tile -> buf1
    COMPUTE(t, 0, qfA, qfB, t + 1);           // even tile from buf0
    __syncthreads();
    if (t + 2 < 32) STAGE(t + 2, 0);          // even tile -> buf0
    COMPUTE(t + 1, 1, qfB, qfA, (t + 2) & 31);// odd tile from buf1
    __syncthreads();
  }
#undef STAGE
#undef LQ
#undef COMPUTE

  // kh=1 waves dump partial sums; kh=0 waves combine and write out
  float* red = (float*)LDSRAW;   // 2 regions x 5120 f32 = 40960 B (fits)
  if (kh == 1) {
#pragma unroll
    for (int reg = 0; reg < 16; ++reg) {
      const int nl = (reg & 3) + 8 * (reg >> 2) + 4 * h;
#pragma unroll
      for (int j = 0; j < 5; ++j)
        red[wn * 5120 + nl * 160 + j * 32 + r] = acc[j][reg];
    }
  }
  __syncthreads();
  if (kh == 0) {
    const float g = gamma[0];
#pragma unroll
    for (int reg = 0; reg < 16; ++reg) {
      const int nl = (reg & 3) + 8 * (reg >> 2) + 4 * h;
      const size_t rowb = ((size_t)(b * NN) + n0 + wn * 32 + nl) * CC + ch * 160 + r;
#pragma unroll
      for (int j = 0; j < 5; ++j) {
        const size_t idx = rowb + (size_t)(j * 32);
        const float s = acc[j][reg] + red[wn * 5120 + nl * 160 + j * 32 + r];
        out[idx] = g * s + x[idx];
      }
    }
  }
}

extern "C" void kernel_launch(void* const* d_in, const int* in_sizes, int n_in,
                              void* d_out, int out_size, void* d_ws, size_t ws_size,
                              hipStream_t stream) {
  const float* x     = (const float*)d_in[0];
  const float* Wq    = (const float*)d_in[1];
  const float* bq    = (const float*)d_in[2];
  const float* Wk    = (const float*)d_in[3];
  const float* bk    = (const float*)d_in[4];
  const float* Wv    = (const float*)d_in[5];
  const float* bv    = (const float*)d_in[6];
  const float* gamma = (const float*)d_in[7];
  float* out = (float*)d_out;

  char* w = (char*)d_ws;
  u16* X3   = (u16*)(w);                       // 512*40*32*8 (10485760 B)
  u16* W3   = (u16*)(w + 10485760);            // 14*40*32*8  (286720 B)
  u16* Qb   = (u16*)(w + 10772480);            // Q3: 8*64*8*32*8 (2097152 B)
  u16* Kb   = (u16*)(w + 12869632);            // 16384*64    (2097152 B)
  u16* Vt   = (u16*)(w + 14966784);            // V3: 8*256*320*8 (10485760 B)
  float* Lb = (float*)(w + 25452544);          // 16384 f32   (65536 B)

  cvt_blk<<<526, 256, 0, stream>>>(x, Wq, Wk, Wv, X3, W3);
  gemm_qkv<<<896, 256, 0, stream>>>(X3, W3, bq, bk, bv, Qb, Kb, Vt);
  row_stats<<<256, 512, 0, stream>>>(Qb, Kb, Lb);
  attn<<<512, 256, 0, stream>>>(Qb, Kb, Vt, Lb, x, gamma, out);
}

// Round 18
// 77.728 us; speedup vs baseline: 1.5165x; 1.0561x over previous
//
#include <hip/hip_runtime.h>
#include <hip/hip_bf16.h>

#define BB 8
#define NN 2048
#define CC 320
#define CQ 64
#define LOG2E 1.4426950408889634f

typedef __attribute__((ext_vector_type(8)))  short bf16x8;
typedef __attribute__((ext_vector_type(4)))  float f32x4;
typedef __attribute__((ext_vector_type(16))) float f32x16;
typedef __attribute__((ext_vector_type(4)))  unsigned short us4;
typedef __attribute__((ext_vector_type(8)))  unsigned short us8;
typedef __attribute__((ext_vector_type(4)))  unsigned int u32x4;
typedef unsigned short u16;

// Layouts:
//  X3[mt=m/32][kk8=k/8][ml=m%32][8]       (bf16; lane-contiguous A-frags)
//  W3[ct=c/32][kk8=k/8][cl=c%32][8]       (bf16; lane-contiguous B-frags)
//  Q3[b][kt=k/32][cq8=cq/8][kl=k%32][8]   (bf16, pre-scaled by log2e)
//  Kb[b*N+n][cq]                          (row-major)
//  V3[b][kt8=k/8][c][8]                   (bf16, UNSCALED — read-only)
//  Lb[b*N+k]                              (f32, log2 of softmax row sum)

static __device__ __forceinline__ u16 f2b(float f) {
  unsigned u = __builtin_bit_cast(unsigned, f);
  unsigned r = (u + 0x7FFFu + ((u >> 16) & 1u)) >> 16;
  return (u16)r;
}
static __device__ __forceinline__ float b2f(u16 s) {
  unsigned u = ((unsigned)s) << 16;
  return __builtin_bit_cast(float, u);
}

static __device__ __forceinline__ f32x16 zero16() {
  f32x16 v = {0,0,0,0, 0,0,0,0, 0,0,0,0, 0,0,0,0};
  return v;
}
static __device__ __forceinline__ f32x4 zero4() {
  f32x4 v = {0,0,0,0};
  return v;
}

static __device__ __forceinline__ void gll16(const void* g, void* l) {
  __builtin_amdgcn_global_load_lds(
      (const __attribute__((address_space(1))) unsigned int*)g,
      (__attribute__((address_space(3))) unsigned int*)l, 16, 0, 0);
}

// 8 fp32 -> bf16x8 via hardware packed converts (RNE, same as f2b)
static __device__ __forceinline__ bf16x8 cvt8(float4 a, float4 b) {
  unsigned p0, p1, p2, p3;
  asm("v_cvt_pk_bf16_f32 %0, %1, %2" : "=v"(p0) : "v"(a.x), "v"(a.y));
  asm("v_cvt_pk_bf16_f32 %0, %1, %2" : "=v"(p1) : "v"(a.z), "v"(a.w));
  asm("v_cvt_pk_bf16_f32 %0, %1, %2" : "=v"(p2) : "v"(b.x), "v"(b.y));
  asm("v_cvt_pk_bf16_f32 %0, %1, %2" : "=v"(p3) : "v"(b.z), "v"(b.w));
  u32x4 w = {p0, p1, p2, p3};
  return __builtin_bit_cast(bf16x8, w);
}

// ---------------------------------------------------------------------------
// K0: fused conversion. blocks 0..511: x -> X3; blocks 512..525: W -> W3.
// grid 526 x 256.
// ---------------------------------------------------------------------------
__global__ __launch_bounds__(256) void cvt_blk(const float* __restrict__ x,
                                               const float* __restrict__ Wq,
                                               const float* __restrict__ Wk,
                                               const float* __restrict__ Wv,
                                               u16* __restrict__ X3,
                                               u16* __restrict__ W3) {
  __shared__ float xs[32][324];   // +4 pad: conflict-free transpose reads
  const int t = threadIdx.x;
  const int bid = blockIdx.x;
  const bool isX = (bid < 512);
  const int b = isX ? bid : (bid - 512);
#pragma unroll
  for (int i = 0; i < 10; ++i) {
    const int lidx = i * 256 + t;        // 0..2559 float4 units
    const int m = lidx / 80;             // 80 float4 per row
    const int kq = lidx - m * 80;
    const float* src;
    if (isX) {
      src = x + (size_t)(b * 32 + m) * CC;
    } else {
      const int row = b * 32 + m;
      src = (row < 64) ? (Wq + (size_t)row * CC)
          : (row < 128) ? (Wk + (size_t)(row - 64) * CC)
                        : (Wv + (size_t)(row - 128) * CC);
    }
    float4 v = *(const float4*)(src + kq * 4);
    *(float4*)&xs[m][kq * 4] = v;
  }
  __syncthreads();
  u16* dst0 = (isX ? X3 : W3) + (size_t)b * 10240;
#pragma unroll
  for (int i = 0; i < 5; ++i) {
    const int u = i * 256 + t;           // 0..1279: kk8*32 + ml
    const int kk8 = u >> 5, ml = u & 31;
    float4 a = *(const float4*)&xs[ml][kk8 * 8];
    float4 c = *(const float4*)&xs[ml][kk8 * 8 + 4];
    bf16x8 o = cvt8(a, c);
    *(bf16x8*)(dst0 + (size_t)u * 8) = o;
  }
}

// ---------------------------------------------------------------------------
// K1: QKV GEMM, wide 128-col wave tiles (4 MFMA per 5 loads). XCD remap.
// grid 512 x 256: slot = colt(4) x yG(16); colt 3 covers only 2 tiles.
// ---------------------------------------------------------------------------
__global__ __launch_bounds__(256) void gemm_qkv(
    const u16* __restrict__ X3, const u16* __restrict__ W3,
    const float* __restrict__ bq, const float* __restrict__ bk,
    const float* __restrict__ bv,
    u16* __restrict__ Qb, u16* __restrict__ Kb, u16* __restrict__ Vt) {
  const int tid = threadIdx.x;
  const int lane = tid & 63, wid = tid >> 6;
  const int r = lane & 31, h = lane >> 5;
  const int bid = blockIdx.x;
  const int xcd = bid & 7;
  const int slot = bid >> 3;          // 0..63
  const int colt = slot & 3;          // 0..3
  const int yG = slot >> 2;           // 0..15
  const int ytile = yG * 8 + xcd;     // 0..127
  const int m0 = ytile * 128 + wid * 32;
  const int col0 = colt * 128;
  const int NT = (colt == 3) ? 2 : 4; // wave-uniform
  const int mt = m0 >> 5;

  const u16* abase = X3 + (size_t)mt * 10240 + (size_t)h * 256 + r * 8;
  const u16* bbase0 = W3 + (size_t)(colt * 4 + 0) * 10240 + (size_t)h * 256 + r * 8;
  const u16* bbase1 = bbase0 + 10240;
  const u16* bbase2 = bbase0 + 20480;
  const u16* bbase3 = bbase0 + 30720;

  f32x16 acc0 = zero16(), acc1 = zero16(), acc2 = zero16(), acc3 = zero16();
  bf16x8 a  = *(const bf16x8*)(abase);
  bf16x8 b0 = *(const bf16x8*)(bbase0);
  bf16x8 b1 = *(const bf16x8*)(bbase1);
  bf16x8 b2, b3;
  if (NT == 4) {
    b2 = *(const bf16x8*)(bbase2);
    b3 = *(const bf16x8*)(bbase3);
  }
#pragma unroll 1
  for (int ks = 0; ks < 20; ++ks) {
    bf16x8 na, nb0, nb1, nb2, nb3;
    if (ks < 19) {
      na  = *(const bf16x8*)(abase  + (ks + 1) * 512);
      nb0 = *(const bf16x8*)(bbase0 + (ks + 1) * 512);
      nb1 = *(const bf16x8*)(bbase1 + (ks + 1) * 512);
      if (NT == 4) {
        nb2 = *(const bf16x8*)(bbase2 + (ks + 1) * 512);
        nb3 = *(const bf16x8*)(bbase3 + (ks + 1) * 512);
      }
    }
    acc0 = __builtin_amdgcn_mfma_f32_32x32x16_bf16(a, b0, acc0, 0, 0, 0);
    acc1 = __builtin_amdgcn_mfma_f32_32x32x16_bf16(a, b1, acc1, 0, 0, 0);
    if (NT == 4) {
      acc2 = __builtin_amdgcn_mfma_f32_32x32x16_bf16(a, b2, acc2, 0, 0, 0);
      acc3 = __builtin_amdgcn_mfma_f32_32x32x16_bf16(a, b3, acc3, 0, 0, 0);
    }
    a = na; b0 = nb0; b1 = nb1;
    if (NT == 4) { b2 = nb2; b3 = nb3; }
  }

  const int bb = m0 >> 11;        // batch
  const int mloc = m0 & 2047;     // n (or k) within batch

#pragma unroll
  for (int nt = 0; nt < 4; ++nt) {
    if (nt >= NT) continue;
    const int tb = col0 + nt * 32;      // tile base column (uniform)
    const int col = tb + r;
    const f32x16 A = (nt == 0) ? acc0 : (nt == 1) ? acc1 : (nt == 2) ? acc2 : acc3;
    if (tb >= 128) {
      // V3[b][kt8][c][8]
      const int c = col - 128;
      const float bias = bv[c];
      u16* vdst = Vt + (((size_t)(bb * 256 + (mloc >> 3)) * 320 + c) * 8) + 4 * h;
#pragma unroll
      for (int g = 0; g < 4; ++g) {
        us4 o;
#pragma unroll
        for (int e = 0; e < 4; ++e) o[e] = f2b(A[g * 4 + e] + bias);
        *(us4*)(vdst + (size_t)g * 2560) = o;
      }
    } else if (tb >= 64) {
      const float bias = bk[col - 64];
#pragma unroll
      for (int reg = 0; reg < 16; ++reg) {
        const int row = m0 + (reg & 3) + 8 * (reg >> 2) + 4 * h;
        Kb[(size_t)row * CQ + (col - 64)] = f2b(A[reg] + bias);
      }
    } else {
      const float bias = bq[col];
      const int kt = mloc >> 5;
      u16* qdst = Qb + (((size_t)(bb * 64 + kt) * 8 + (col >> 3)) * 32) * 8 + (col & 7);
#pragma unroll
      for (int reg = 0; reg < 16; ++reg) {
        const int kl = (reg & 3) + 8 * (reg >> 2) + 4 * h;
        qdst[kl * 8] = f2b((A[reg] + bias) * LOG2E);
      }
    }
  }
}

// ---------------------------------------------------------------------------
// K3: row sums -> Lb[k] = log2(S[k]). 8 waves (512 thr), grid 256.
// ---------------------------------------------------------------------------
__global__ __launch_bounds__(512) void row_stats(
    const u16* __restrict__ Qb, const u16* __restrict__ Kb,
    float* __restrict__ Lb) {
  __shared__ float Sp[8][64];
  const int tid = threadIdx.x;
  const int lane = tid & 63, wid = tid >> 6;   // 0..7
  const int rl = lane & 15, hq = lane >> 4;
  const int bid = blockIdx.x;
  const int batch = bid & 7;
  const int kloc64 = (bid >> 3) * 64;          // bid>>3 in [0,32)

  bf16x8 af[4][2];
#pragma unroll
  for (int mt = 0; mt < 4; ++mt) {
    const int k_loc = kloc64 + mt * 16 + rl;
    const int kt = k_loc >> 5, kl = k_loc & 31;
#pragma unroll
    for (int qs = 0; qs < 2; ++qs)
      af[mt][qs] = *(const bf16x8*)(Qb +
          (((size_t)(batch * 64 + kt) * 8 + qs * 4 + hq) * 32 + kl) * 8);
  }

  float S[4][4];
#pragma unroll
  for (int mt = 0; mt < 4; ++mt)
#pragma unroll
    for (int rr = 0; rr < 4; ++rr) S[mt][rr] = 0.f;

  const int mstart = batch * NN + wid * 256;
  const u16* kr = Kb + (size_t)(mstart + rl) * CQ + hq * 8;
  bf16x8 c0 = *(const bf16x8*)(kr);
  bf16x8 c1 = *(const bf16x8*)(kr + 32);
#pragma unroll 1
  for (int ms = 0; ms < 16; ++ms) {
    bf16x8 n0, n1;
    if (ms < 15) {
      n0 = *(const bf16x8*)(kr + 16 * CQ);
      n1 = *(const bf16x8*)(kr + 16 * CQ + 32);
    }
#pragma unroll
    for (int mt = 0; mt < 4; ++mt) {
      f32x4 e = zero4();
      e = __builtin_amdgcn_mfma_f32_16x16x32_bf16(af[mt][0], c0, e, 0, 0, 0);
      e = __builtin_amdgcn_mfma_f32_16x16x32_bf16(af[mt][1], c1, e, 0, 0, 0);
#pragma unroll
      for (int rr = 0; rr < 4; ++rr) S[mt][rr] += __builtin_amdgcn_exp2f(e[rr]);
    }
    c0 = n0; c1 = n1; kr += 16 * CQ;
  }

#pragma unroll
  for (int d = 1; d < 16; d <<= 1)
#pragma unroll
    for (int mt = 0; mt < 4; ++mt)
#pragma unroll
      for (int rr = 0; rr < 4; ++rr) S[mt][rr] += __shfl_xor(S[mt][rr], d, 64);

  if (rl == 0) {
#pragma unroll
    for (int mt = 0; mt < 4; ++mt)
#pragma unroll
      for (int rr = 0; rr < 4; ++rr) Sp[wid][mt * 16 + hq * 4 + rr] = S[mt][rr];
  }
  __syncthreads();
  if (tid < 64) {
    float s = 0.f;
#pragma unroll
    for (int p = 0; p < 8; ++p) s += Sp[p][tid];
    Lb[batch * NN + kloc64 + tid] = __log2f(s);
  }
}

// ---------------------------------------------------------------------------
// K4: attention v13 — r17-passing kernel + s_setprio(1) around the PV MFMA
// cluster (T5; 2 staggered blocks/CU give the scheduler role diversity).
// Everything else byte-identical to r17.
// ---------------------------------------------------------------------------
__global__ __launch_bounds__(256, 2) void attn(
    const u16* __restrict__ Qb, const u16* __restrict__ Kb,
    const u16* __restrict__ Vt, const float* __restrict__ Lb,
    const float* __restrict__ x, const float* __restrict__ gamma,
    float* __restrict__ out) {
  __shared__ __align__(16) char LDSRAW[49152];   // 40KB V bufs + 8KB L
  float* Ls = (float*)(LDSRAW + 40960);          // [2048] = both kh halves
  const int tid = threadIdx.x;
  const int lane = tid & 63, wid = tid >> 6;
  const int wn = wid >> 1;       // n-tile within pair
  const int kh = wid & 1;        // k-half
  const int r = lane & 31, h = lane >> 5;
  const int bid = blockIdx.x;
  const int b = bid & 7;
  const int rest = bid >> 3;
  const int ch = rest & 1;
  const int n0 = (rest >> 1) * 64;

  // one-time: stage this batch's L (2048 f32, 8 KB) into LDS
#pragma unroll
  for (int i = 0; i < 8; ++i)
    Ls[i * 256 + tid] = Lb[b * NN + i * 256 + tid];

  // K fragments for n-tile n0 + wn*32 (held all k)
  bf16x8 kf[4];
  {
    const u16* krow = Kb + (size_t)(b * NN + n0 + wn * 32 + r) * CQ + h * 8;
#pragma unroll
    for (int qs = 0; qs < 4; ++qs) kf[qs] = *(const bf16x8*)(krow + qs * 16);
  }

  f32x16 acc[5];
#pragma unroll
  for (int j = 0; j < 5; ++j) acc[j] = zero16();

  // per-wave bases for this k-half
  const u16* qb3 = Qb + ((size_t)(b * 64 + kh * 32) * 8) * 256 + (size_t)r * 8;
  const float* lsb = Ls + kh * 1024 + 4 * h;   // LDS pointer (per-lane via h)

  // stage V only: 20 chunks of 1KB (10 per kh), wave w takes [w*5, w*5+5)
#define STAGE(TN, BUF) {                                                       \
    _Pragma("unroll")                                                          \
    for (int i_ = 0; i_ < 5; ++i_) {                                           \
      const int c_ = wid * 5 + i_;                                             \
      const int khc_ = c_ / 10;                                                \
      const int rem_ = c_ % 10;                                                \
      char* dst_ = LDSRAW + (BUF) * 20480 + khc_ * 10240 + rem_ * 1024;        \
      const int off_ = rem_ * 512 + lane * 8;                                  \
      const int row_ = off_ / 1280;                                            \
      const int win_ = off_ - row_ * 1280;                                     \
      const u16* src_ = Vt +                                                   \
          ((size_t)(b * 256 + khc_ * 128 + (TN) * 4 + row_) * 320              \
           + ch * 160) * 8 + win_;                                             \
      gll16(src_, dst_);                                                       \
    }                                                                          \
  }

// prefetch Q frags for tile TN into QN (plain global loads, lane-contiguous)
#define LQ(QN, TN) {                                                           \
    _Pragma("unroll")                                                          \
    for (int qs = 0; qs < 4; ++qs)                                             \
      QN[qs] = *(const bf16x8*)(qb3 + ((size_t)(TN) * 8 + qs * 2 + h) * 256);  \
  }

// compute tile T from LDS buffer BUF using prefetched QF; prefetch QN (TNX);
// L read from LDS (broadcast ds_read, lgkm queue)
#define COMPUTE(T, BUF, QF, QN, TNX) {                                         \
    LQ(QN, TNX)                                                                \
    float4 LF0 = *(const float4*)(lsb + (T) * 32);                             \
    float4 LF1 = *(const float4*)(lsb + (T) * 32 + 8);                         \
    float4 LF2 = *(const float4*)(lsb + (T) * 32 + 16);                        \
    float4 LF3 = *(const float4*)(lsb + (T) * 32 + 24);                        \
    const char* base_ = LDSRAW + (BUF) * 20480 + kh * 10240;                   \
    f32x16 e = zero16();                                                       \
    _Pragma("unroll")                                                          \
    for (int qs = 0; qs < 4; ++qs)                                             \
      e = __builtin_amdgcn_mfma_f32_32x32x16_bf16(QF[qs], kf[qs], e, 0, 0, 0); \
    bf16x8 vf[5][2];                                                           \
    _Pragma("unroll")                                                          \
    for (int j = 0; j < 5; ++j)                                                \
      _Pragma("unroll")                                                        \
      for (int ks = 0; ks < 2; ++ks)                                           \
        vf[j][ks] = *(const bf16x8*)(base_ + (ks * 2 + h) * 2560               \
                                     + (j * 32 + r) * 16);                     \
    unsigned pk0, pk1, pk2, pk3, pk4, pk5, pk6, pk7;                           \
    { float l0 = __builtin_amdgcn_exp2f(e[0]  - LF0.x);                        \
      float h0 = __builtin_amdgcn_exp2f(e[1]  - LF0.y);                        \
      float l1 = __builtin_amdgcn_exp2f(e[2]  - LF0.z);                        \
      float h1 = __builtin_amdgcn_exp2f(e[3]  - LF0.w);                        \
      float l2 = __builtin_amdgcn_exp2f(e[4]  - LF1.x);                        \
      float h2 = __builtin_amdgcn_exp2f(e[5]  - LF1.y);                        \
      float l3 = __builtin_amdgcn_exp2f(e[6]  - LF1.z);                        \
      float h3 = __builtin_amdgcn_exp2f(e[7]  - LF1.w);                        \
      float l4 = __builtin_amdgcn_exp2f(e[8]  - LF2.x);                        \
      float h4 = __builtin_amdgcn_exp2f(e[9]  - LF2.y);                        \
      float l5 = __builtin_amdgcn_exp2f(e[10] - LF2.z);                        \
      float h5 = __builtin_amdgcn_exp2f(e[11] - LF2.w);                        \
      float l6 = __builtin_amdgcn_exp2f(e[12] - LF3.x);                        \
      float h6 = __builtin_amdgcn_exp2f(e[13] - LF3.y);                        \
      float l7 = __builtin_amdgcn_exp2f(e[14] - LF3.z);                        \
      float h7 = __builtin_amdgcn_exp2f(e[15] - LF3.w);                        \
      asm("v_cvt_pk_bf16_f32 %0, %1, %2" : "=v"(pk0) : "v"(l0), "v"(h0));      \
      asm("v_cvt_pk_bf16_f32 %0, %1, %2" : "=v"(pk1) : "v"(l1), "v"(h1));      \
      asm("v_cvt_pk_bf16_f32 %0, %1, %2" : "=v"(pk2) : "v"(l2), "v"(h2));      \
      asm("v_cvt_pk_bf16_f32 %0, %1, %2" : "=v"(pk3) : "v"(l3), "v"(h3));      \
      asm("v_cvt_pk_bf16_f32 %0, %1, %2" : "=v"(pk4) : "v"(l4), "v"(h4));      \
      asm("v_cvt_pk_bf16_f32 %0, %1, %2" : "=v"(pk5) : "v"(l5), "v"(h5));      \
      asm("v_cvt_pk_bf16_f32 %0, %1, %2" : "=v"(pk6) : "v"(l6), "v"(h6));      \
      asm("v_cvt_pk_bf16_f32 %0, %1, %2" : "=v"(pk7) : "v"(l7), "v"(h7)); }    \
    asm("v_permlane32_swap_b32 %0, %1" : "+v"(pk0), "+v"(pk2));                \
    asm("v_permlane32_swap_b32 %0, %1" : "+v"(pk1), "+v"(pk3));                \
    asm("v_permlane32_swap_b32 %0, %1" : "+v"(pk4), "+v"(pk6));                \
    asm("v_permlane32_swap_b32 %0, %1" : "+v"(pk5), "+v"(pk7));                \
    u32x4 w0_ = {pk0, pk1, pk2, pk3};                                          \
    u32x4 w1_ = {pk4, pk5, pk6, pk7};                                          \
    bf16x8 pa0 = __builtin_bit_cast(bf16x8, w0_);                              \
    bf16x8 pa1 = __builtin_bit_cast(bf16x8, w1_);                              \
    __builtin_amdgcn_s_setprio(1);                                             \
    _Pragma("unroll")                                                          \
    for (int j = 0; j < 5; ++j) {                                              \
      acc[j] = __builtin_amdgcn_mfma_f32_32x32x16_bf16(pa0, vf[j][0], acc[j], 0, 0, 0); \
      acc[j] = __builtin_amdgcn_mfma_f32_32x32x16_bf16(pa1, vf[j][1], acc[j], 0, 0, 0); \
    }                                                                          \
    __builtin_amdgcn_s_setprio(0);                                             \
  }

  bf16x8 qfA[4], qfB[4];

  STAGE(0, 0);
  LQ(qfA, 0)
  __syncthreads();                 // V tile 0 staged + Ls filled (all waves)
#pragma unroll 1
  for (int t = 0; t < 32; t += 2) {
    STAGE(t + 1, 1);                          // odd tile -> buf1
    COMPUTE(t, 0, qfA, qfB, t + 1);           // even tile from buf0
    __syncthreads();
    if (t + 2 < 32) STAGE(t + 2, 0);          // even tile -> buf0
    COMPUTE(t + 1, 1, qfB, qfA, (t + 2) & 31);// odd tile from buf1
    __syncthreads();
  }
#undef STAGE
#undef LQ
#undef COMPUTE

  // kh=1 waves dump partial sums; kh=0 waves combine and write out
  float* red = (float*)LDSRAW;   // 2 regions x 5120 f32 = 40960 B (fits)
  if (kh == 1) {
#pragma unroll
    for (int reg = 0; reg < 16; ++reg) {
      const int nl = (reg & 3) + 8 * (reg >> 2) + 4 * h;
#pragma unroll
      for (int j = 0; j < 5; ++j)
        red[wn * 5120 + nl * 160 + j * 32 + r] = acc[j][reg];
    }
  }
  __syncthreads();
  if (kh == 0) {
    const float g = gamma[0];
#pragma unroll
    for (int reg = 0; reg < 16; ++reg) {
      const int nl = (reg & 3) + 8 * (reg >> 2) + 4 * h;
      const size_t rowb = ((size_t)(b * NN) + n0 + wn * 32 + nl) * CC + ch * 160 + r;
#pragma unroll
      for (int j = 0; j < 5; ++j) {
        const size_t idx = rowb + (size_t)(j * 32);
        const float s = acc[j][reg] + red[wn * 5120 + nl * 160 + j * 32 + r];
        out[idx] = g * s + x[idx];
      }
    }
  }
}

extern "C" void kernel_launch(void* const* d_in, const int* in_sizes, int n_in,
                              void* d_out, int out_size, void* d_ws, size_t ws_size,
                              hipStream_t stream) {
  const float* x     = (const float*)d_in[0];
  const float* Wq    = (const float*)d_in[1];
  const float* bq    = (const float*)d_in[2];
  const float* Wk    = (const float*)d_in[3];
  const float* bk    = (const float*)d_in[4];
  const float* Wv    = (const float*)d_in[5];
  const float* bv    = (const float*)d_in[6];
  const float* gamma = (const float*)d_in[7];
  float* out = (float*)d_out;

  char* w = (char*)d_ws;
  u16* X3   = (u16*)(w);                       // 512*40*32*8 (10485760 B)
  u16* W3   = (u16*)(w + 10485760);            // 14*40*32*8  (286720 B)
  u16* Qb   = (u16*)(w + 10772480);            // Q3: 8*64*8*32*8 (2097152 B)
  u16* Kb   = (u16*)(w + 12869632);            // 16384*64    (2097152 B)
  u16* Vt   = (u16*)(w + 14966784);            // V3: 8*256*320*8 (10485760 B)
  float* Lb = (float*)(w + 25452544);          // 16384 f32   (65536 B)

  cvt_blk<<<526, 256, 0, stream>>>(x, Wq, Wk, Wv, X3, W3);
  gemm_qkv<<<512, 256, 0, stream>>>(X3, W3, bq, bk, bv, Qb, Kb, Vt);
  row_stats<<<256, 512, 0, stream>>>(Qb, Kb, Lb);
  attn<<<512, 256, 0, stream>>>(Qb, Kb, Vt, Lb, x, gamma, out);
}